// Round 11
// baseline (812.728 us; speedup 1.0000x reference)
//
#include <hip/hip_runtime.h>
#include <hip/hip_bf16.h>
#include <stdint.h>

#define B_ 8
#define N_ 4096
#define T_ 512
#define M_ 4096
#define KVB 32
#define NBLK 64
#define NT 128            // 32-m tiles
#define KT_F16 (KVB*T_)   // 16384 f16 = 32KB per packed K tile
#define VT_F16 (T_*KVB)   // 16384 f16 = 32KB per packed V tile

typedef _Float16 f16;
typedef __attribute__((ext_vector_type(8))) f16 f16x8;
typedef __attribute__((ext_vector_type(4))) f16 f16x4;
typedef __attribute__((ext_vector_type(4))) float f32x4;

__device__ __forceinline__ void gld16(const void* g, void* l) {
  __builtin_amdgcn_global_load_lds(
      (const __attribute__((address_space(1))) unsigned int*)g,
      (__attribute__((address_space(3))) unsigned int*)l, 16, 0, 0);
}

// ---------------- pack kernels (identical to R3..R10, proven) ----------------
__global__ __launch_bounds__(256) void pack_k(const float* __restrict__ Kg,
                                              f16* __restrict__ pk) {
  const int bx = blockIdx.x;
  const int ts = bx & 7;
  const int mt = (bx >> 3) & (NT - 1);
  const int b  = bx >> 10;
  const int m0 = mt * KVB;
  const int tid = threadIdx.x;
  __shared__ float tileT[64][33];
  {
    const int tl = tid >> 2;
    const int mseg = (tid & 3) * 8;
    const float* src = Kg + (size_t)(b * T_ + ts * 64 + tl) * M_ + m0 + mseg;
    const float4 a = *reinterpret_cast<const float4*>(src);
    const float4 c = *reinterpret_cast<const float4*>(src + 4);
    tileT[tl][mseg + 0] = a.x; tileT[tl][mseg + 1] = a.y;
    tileT[tl][mseg + 2] = a.z; tileT[tl][mseg + 3] = a.w;
    tileT[tl][mseg + 4] = c.x; tileT[tl][mseg + 5] = c.y;
    tileT[tl][mseg + 6] = c.z; tileT[tl][mseg + 7] = c.w;
  }
  __syncthreads();
  {
    const int m  = tid >> 3;
    const int jl = tid & 7;
    const int tlc = (jl ^ (m & 7)) * 8;
    f16x8 o;
    #pragma unroll
    for (int i = 0; i < 8; ++i) o[i] = (f16)tileT[tlc + i][m];
    f16* dst = pk + ((size_t)(b * NT + mt) * KVB + m) * T_ + (ts * 8 + jl) * 8;
    *reinterpret_cast<f16x8*>(dst) = o;
  }
}

__global__ __launch_bounds__(256) void pack_v(const float* __restrict__ Vg,
                                              f16* __restrict__ pv) {
  const int bx = blockIdx.x;        // b*NT + mt
  const int mt = bx & (NT - 1);
  const int b  = bx >> 7;
  const int m0 = mt * KVB;
  const int tid = threadIdx.x;
  #pragma unroll
  for (int it = 0; it < 8; ++it) {
    const int task = it * 256 + tid;      // 0..2047
    const int ts = task >> 6;
    const int ln = task & 63;
    const int t  = ts * 16 + (ln & 15);
    const int mc = (ln >> 4) * 8;
    const float* src = Vg + (size_t)(b * T_ + t) * M_ + m0 + mc;
    const float4 a = *reinterpret_cast<const float4*>(src);
    const float4 d = *reinterpret_cast<const float4*>(src + 4);
    f16x8 o;
    o[0] = (f16)a.x; o[1] = (f16)a.y; o[2] = (f16)a.z; o[3] = (f16)a.w;
    o[4] = (f16)d.x; o[5] = (f16)d.y; o[6] = (f16)d.z; o[7] = (f16)d.w;
    *reinterpret_cast<f16x8*>(pv + ((size_t)bx * 2048 + task) * 8) = o;
  }
}

// ------- main: producer-consumer. waves 0-3 = S/softmax, waves 4-7 = PV -------
__global__ __launch_bounds__(512, 2) void fattn(
    const float* __restrict__ Qg, const f16* __restrict__ pk,
    const f16* __restrict__ pv, float* __restrict__ Og)
{
  __shared__ __align__(16) f16 Ks[2][KT_F16];    // 64KB dbuf
  __shared__ __align__(16) f16 Ps[2][NBLK * 32]; // 2 x 4KB: [n][m], 64B rows, chunk-XOR
  __shared__ float redmax[2][NBLK];
  __shared__ float redsum[2][NBLK];
  __shared__ float stat_al[2][NBLK];
  __shared__ float stat_il[NBLK];

  const int raw = blockIdx.x;
  const int bid = (raw & 7) * 64 + (raw >> 3);   // XCD <-> batch (L2 locality)
  const int b   = bid >> 6;
  const int nb  = (bid & 63) << 6;
  const int tid  = threadIdx.x;
  const int wv   = tid >> 6;
  const int lane = tid & 63;
  const int l15  = lane & 15;
  const int lq   = lane >> 4;

  const char* kbase = (const char*)(pk + (size_t)b * NT * KT_F16);
  const f16*  pvb   = pv + (size_t)b * NT * VT_F16;
  const int lo = wv * 4096;                      // per-wave 4KB slice of a 32KB tile

  // prologue: all 8 waves stage K tile 0 -> buf0
  #pragma unroll
  for (int r = 0; r < 4; ++r)
    gld16(kbase + lo + r * 1024 + lane * 16, (char*)&Ks[0][0] + lo + r * 1024 + lane * 16);

  if (wv < 4) {
    // ================== S-GROUP: wave = (nh = wv>>1, mh = wv&1) ==================
    const int nh = wv >> 1;       // 32-n half
    const int mh = wv & 1;        // 16-m half of the 32-m tile
    const int n0 = nh * 32 + l15;
    const int n1 = n0 + 16;

    // Q fragments: two 16-n sets, fp16 (validated numerics: absmax 0.047 < 0.1025)
    f16x8 qh0[16], qh1[16];
    {
      const float* qrow0 = Qg + (size_t)(b * N_ + nb + nh * 32 + l15) * T_;
      const float* qrow1 = qrow0 + (size_t)16 * T_;
      #pragma unroll
      for (int ks = 0; ks < 16; ++ks) {
        const int k0 = ks * 32 + lq * 8;
        float f[8];
        *reinterpret_cast<float4*>(&f[0]) = *reinterpret_cast<const float4*>(qrow0 + k0);
        *reinterpret_cast<float4*>(&f[4]) = *reinterpret_cast<const float4*>(qrow0 + k0 + 4);
        f16x8 h;
        #pragma unroll
        for (int j = 0; j < 8; ++j) h[j] = (f16)f[j];
        qh0[ks] = h;
        *reinterpret_cast<float4*>(&f[0]) = *reinterpret_cast<const float4*>(qrow1 + k0);
        *reinterpret_cast<float4*>(&f[4]) = *reinterpret_cast<const float4*>(qrow1 + k0 + 4);
        #pragma unroll
        for (int j = 0; j < 8; ++j) h[j] = (f16)f[j];
        qh1[ks] = h;
      }
    }

    float m_run0 = -INFINITY, m_run1 = -INFINITY;
    float l_par0 = 0.f, l_par1 = 0.f;   // per-lane partial (n, lq-quarter of m)

    const int mrow = mh * 16 + l15;     // row in [0,32)
    const int mb = mrow * T_;
    const int mx = l15 & 7;

    __syncthreads();   // K0 resident

    for (int dt = 0; dt < NT; ++dt) {
      const int cur = dt & 1;
      if (dt + 1 < NT) {
        const char* kt = kbase + (size_t)(dt + 1) * (KT_F16 * 2);
        char* kd = (char*)&Ks[cur ^ 1][0];
        #pragma unroll
        for (int r = 0; r < 4; ++r)
          gld16(kt + lo + r * 1024 + lane * 16, kd + lo + r * 1024 + lane * 16);
      }

      // phase1: S^T — ONE A-read feeds both n-subgroups
      f32x4 s0 = f32x4{0.f, 0.f, 0.f, 0.f};
      f32x4 s1 = f32x4{0.f, 0.f, 0.f, 0.f};
      {
        const f16* KsC = &Ks[cur][0];
        __builtin_amdgcn_s_setprio(1);
        #pragma unroll
        for (int ks = 0; ks < 16; ++ks) {
          const int c = ((ks << 2) + lq) ^ mx;
          const f16x8 a = *reinterpret_cast<const f16x8*>(KsC + mb + c * 8);
          s0 = __builtin_amdgcn_mfma_f32_16x16x32_f16(a, qh0[ks], s0, 0, 0, 0);
          s1 = __builtin_amdgcn_mfma_f32_16x16x32_f16(a, qh1[ks], s1, 0, 0, 0);
        }
        __builtin_amdgcn_s_setprio(0);
      }
      float t0 = fmaxf(fmaxf(s0[0], s0[1]), fmaxf(s0[2], s0[3]));
      float t1 = fmaxf(fmaxf(s1[0], s1[1]), fmaxf(s1[2], s1[3]));
      t0 = fmaxf(t0, __shfl_xor(t0, 16)); t0 = fmaxf(t0, __shfl_xor(t0, 32));
      t1 = fmaxf(t1, __shfl_xor(t1, 16)); t1 = fmaxf(t1, __shfl_xor(t1, 32));
      if (lane < 16) {
        redmax[mh][nh * 32 + lane] = t0;
        redmax[mh][nh * 32 + 16 + lane] = t1;
      }
      asm volatile("s_waitcnt lgkmcnt(0)" ::: "memory");
      __builtin_amdgcn_s_barrier();                      // B1
      __builtin_amdgcn_sched_barrier(0);

      // phase2: softmax (PV-group is doing PV(dt-1) concurrently)
      const float g0 = fmaxf(redmax[0][n0], redmax[1][n0]);
      const float g1 = fmaxf(redmax[0][n1], redmax[1][n1]);
      const float mnew0 = fmaxf(m_run0, g0);
      const float mnew1 = fmaxf(m_run1, g1);
      const float alpha0 = __expf(m_run0 - mnew0);       // first tile: 0
      const float alpha1 = __expf(m_run1 - mnew1);
      if (mh == 0 && lane < 16) {
        stat_al[cur][nh * 32 + lane] = alpha0;
        stat_al[cur][nh * 32 + 16 + lane] = alpha1;
      }
      const float e00 = __expf(s0[0] - mnew0);
      const float e01 = __expf(s0[1] - mnew0);
      const float e02 = __expf(s0[2] - mnew0);
      const float e03 = __expf(s0[3] - mnew0);
      const float e10 = __expf(s1[0] - mnew1);
      const float e11 = __expf(s1[1] - mnew1);
      const float e12 = __expf(s1[2] - mnew1);
      const float e13 = __expf(s1[3] - mnew1);
      l_par0 = l_par0 * alpha0 + ((e00 + e01) + (e02 + e03));
      l_par1 = l_par1 * alpha1 + ((e10 + e11) + (e12 + e13));
      m_run0 = mnew0; m_run1 = mnew1;
      {
        f16x4 w0, w1;
        w0[0] = (f16)e00; w0[1] = (f16)e01; w0[2] = (f16)e02; w0[3] = (f16)e03;
        w1[0] = (f16)e10; w1[1] = (f16)e11; w1[2] = (f16)e12; w1[3] = (f16)e13;
        const int ch = mh * 2 + (lq >> 1);
        const int e = (lq & 1) * 4;
        *reinterpret_cast<f16x4*>(&Ps[cur][n0 * 32 + ((ch ^ ((n0 >> 1) & 3)) * 8) + e]) = w0;
        *reinterpret_cast<f16x4*>(&Ps[cur][n1 * 32 + ((ch ^ ((n1 >> 1) & 3)) * 8) + e]) = w1;
      }
      asm volatile("s_waitcnt lgkmcnt(0) vmcnt(0)" ::: "memory");
      __builtin_amdgcn_s_barrier();                      // EB
      __builtin_amdgcn_sched_barrier(0);
    }

    // epilogue: reduce l over lq, publish 1/l
    l_par0 += __shfl_xor(l_par0, 16); l_par0 += __shfl_xor(l_par0, 32);
    l_par1 += __shfl_xor(l_par1, 16); l_par1 += __shfl_xor(l_par1, 32);
    if (lane < 16) {
      redsum[mh][nh * 32 + lane] = l_par0;
      redsum[mh][nh * 32 + 16 + lane] = l_par1;
    }
    __syncthreads();   // X1
    if (mh == 0 && lane < 16) {
      const int na = nh * 32 + lane;
      const int nbq = na + 16;
      stat_il[na] = 1.0f / (redsum[0][na] + redsum[1][na]);
      stat_il[nbq] = 1.0f / (redsum[0][nbq] + redsum[1][nbq]);
    }
    __syncthreads();   // X2
  } else {
    // ================== PV-GROUP: wave owns t in [(wv-4)*128, +128) ==================
    const int pw = wv - 4;
    const int tb = pw * 128;

    f32x4 oacc[8][4];
    #pragma unroll
    for (int tf = 0; tf < 8; ++tf)
      #pragma unroll
      for (int nf = 0; nf < 4; ++nf)
        oacc[tf][nf] = f32x4{0.f, 0.f, 0.f, 0.f};
    f16x8 vfr[2][8];

    __syncthreads();   // K0 resident

    for (int dt = 0; dt < NT; ++dt) {
      const int cur = dt & 1;
      const int prv = cur ^ 1;
      // K staging share FIRST (FIFO: drained by vmcnt(8) at EB)
      if (dt + 1 < NT) {
        const char* kt = kbase + (size_t)(dt + 1) * (KT_F16 * 2);
        char* kd = (char*)&Ks[cur ^ 1][0];
        #pragma unroll
        for (int r = 0; r < 4; ++r)
          gld16(kt + lo + r * 1024 + lane * 16, kd + lo + r * 1024 + lane * 16);
      }
      // phase1: issue V(dt) -> vfr[cur]; rescale oacc by alpha(dt-1)
      {
        const f16* vt = pvb + (size_t)dt * 2048 * 8;
        #pragma unroll
        for (int tf = 0; tf < 8; ++tf)
          vfr[cur][tf] = *reinterpret_cast<const f16x8*>(
              vt + ((size_t)(pw * 8 + tf) * 64 + lane) * 8);
      }
      if (dt > 0) {
        const float al0 = stat_al[prv][l15];
        const float al1 = stat_al[prv][16 + l15];
        const float al2 = stat_al[prv][32 + l15];
        const float al3 = stat_al[prv][48 + l15];
        if (__any((al0 != 1.0f) || (al1 != 1.0f) || (al2 != 1.0f) || (al3 != 1.0f))) {
          #pragma unroll
          for (int nf = 0; nf < 4; ++nf) {
            const float av = nf == 0 ? al0 : (nf == 1 ? al1 : (nf == 2 ? al2 : al3));
            #pragma unroll
            for (int tf = 0; tf < 8; ++tf) {
              oacc[tf][nf][0] *= av; oacc[tf][nf][1] *= av;
              oacc[tf][nf][2] *= av; oacc[tf][nf][3] *= av;
            }
          }
        }
      }
      __builtin_amdgcn_s_barrier();                      // B1
      __builtin_amdgcn_sched_barrier(0);

      // phase2: PV(dt-1) while S-group does softmax(dt)
      if (dt > 0) {
        __builtin_amdgcn_s_setprio(1);
        #pragma unroll
        for (int nf = 0; nf < 4; ++nf) {
          const int n2 = nf * 16 + l15;
          const f16x8 pfr = *reinterpret_cast<const f16x8*>(
              &Ps[prv][n2 * 32 + (lq ^ ((n2 >> 1) & 3)) * 8]);
          #pragma unroll
          for (int tf = 0; tf < 8; ++tf)
            oacc[tf][nf] = __builtin_amdgcn_mfma_f32_16x16x32_f16(vfr[prv][tf], pfr, oacc[tf][nf], 0, 0, 0);
        }
        __builtin_amdgcn_s_setprio(0);
      }
      asm volatile("s_waitcnt vmcnt(8)" ::: "memory");   // drain K(dt+1); V stays
      __builtin_amdgcn_s_barrier();                      // EB
      __builtin_amdgcn_sched_barrier(0);
    }

    // epilogue: final PV(NT-1), then scale + store
    {
      const int prv = (NT - 1) & 1;
      const float al0 = stat_al[prv][l15];
      const float al1 = stat_al[prv][16 + l15];
      const float al2 = stat_al[prv][32 + l15];
      const float al3 = stat_al[prv][48 + l15];
      if (__any((al0 != 1.0f) || (al1 != 1.0f) || (al2 != 1.0f) || (al3 != 1.0f))) {
        #pragma unroll
        for (int nf = 0; nf < 4; ++nf) {
          const float av = nf == 0 ? al0 : (nf == 1 ? al1 : (nf == 2 ? al2 : al3));
          #pragma unroll
          for (int tf = 0; tf < 8; ++tf) {
            oacc[tf][nf][0] *= av; oacc[tf][nf][1] *= av;
            oacc[tf][nf][2] *= av; oacc[tf][nf][3] *= av;
          }
        }
      }
      #pragma unroll
      for (int nf = 0; nf < 4; ++nf) {
        const int n2 = nf * 16 + l15;
        const f16x8 pfr = *reinterpret_cast<const f16x8*>(
            &Ps[prv][n2 * 32 + (lq ^ ((n2 >> 1) & 3)) * 8]);
        #pragma unroll
        for (int tf = 0; tf < 8; ++tf)
          oacc[tf][nf] = __builtin_amdgcn_mfma_f32_16x16x32_f16(vfr[prv][tf], pfr, oacc[tf][nf], 0, 0, 0);
      }
    }
    __syncthreads();   // X1 (match S-group)
    __syncthreads();   // X2 (stat_il committed)
    #pragma unroll
    for (int nf = 0; nf < 4; ++nf) {
      const float il = stat_il[nf * 16 + l15];
      const size_t base = (size_t)(b * N_ + nb + nf * 16 + l15) * T_;
      #pragma unroll
      for (int tf = 0; tf < 8; ++tf) {
        const int t = tb + tf * 16 + lq * 4;
        float4 o;
        o.x = oacc[tf][nf][0] * il;
        o.y = oacc[tf][nf][1] * il;
        o.z = oacc[tf][nf][2] * il;
        o.w = oacc[tf][nf][3] * il;
        *reinterpret_cast<float4*>(Og + base + t) = o;
      }
    }
  }
}

// ---------------- fallback (R2-proven, no ws): 8-wave 64-n block ----------------
#define KSTR 520
#define PSTRF 48
__global__ __launch_bounds__(512, 2) void fattn_fb(
    const float* __restrict__ Qg, const float* __restrict__ Kg,
    const float* __restrict__ Vg, float* __restrict__ Og)
{
  __shared__ __align__(16) f16 Ksf[KVB * KSTR];
  __shared__ __align__(16) f16 Vsf[T_ * KVB];
  __shared__ __align__(16) f16 Psf[64 * PSTRF];
  __shared__ float redmax[2][64];
  __shared__ float redsum[2][64];
  __shared__ float stat_al[64];
  __shared__ float stat_il[64];

  const int bid  = blockIdx.x;
  const int b    = bid >> 6;
  const int nb   = (bid & 63) << 6;
  const int tid  = threadIdx.x;
  const int w    = tid >> 6;
  const int lane = tid & 63;
  const int l15  = lane & 15;
  const int lq   = lane >> 4;
  const int ms   = w & 1;
  const int ng   = w >> 1;

  f16x8 qh[16], ql[16];
  {
    const float* qrow = Qg + (size_t)(b * N_ + nb + ng * 16 + l15) * T_;
    #pragma unroll
    for (int ks = 0; ks < 16; ++ks) {
      const int k0 = ks * 32 + lq * 8;
      float f[8];
      *reinterpret_cast<float4*>(&f[0]) = *reinterpret_cast<const float4*>(qrow + k0);
      *reinterpret_cast<float4*>(&f[4]) = *reinterpret_cast<const float4*>(qrow + k0 + 4);
      f16x8 h, l;
      #pragma unroll
      for (int j = 0; j < 8; ++j) { h[j] = (f16)f[j]; l[j] = (f16)(f[j] - (float)h[j]); }
      qh[ks] = h; ql[ks] = l;
    }
  }
  f32x4 oacc[4][4];
  #pragma unroll
  for (int tf = 0; tf < 4; ++tf)
    #pragma unroll
    for (int nf = 0; nf < 4; ++nf)
      oacc[tf][nf] = f32x4{0.f, 0.f, 0.f, 0.f};
  float m_run = -INFINITY, l_run = 0.f;

  for (int mt = 0; mt < M_ / KVB; ++mt) {
    const int m0 = mt * KVB;
    #pragma unroll
    for (int r = 0; r < 8; ++r) {
      const int task = r * 512 + tid;
      const int m  = task & 31;
      const int t0 = (task >> 5) << 2;
      const float* src = Kg + (size_t)(b * T_ + t0) * M_ + m0 + m;
      f16x4 kk;
      kk[0] = (f16)src[0]; kk[1] = (f16)src[M_];
      kk[2] = (f16)src[2 * M_]; kk[3] = (f16)src[3 * M_];
      *reinterpret_cast<f16x4*>(&Ksf[m * KSTR + t0]) = kk;
    }
    #pragma unroll
    for (int r = 0; r < 4; ++r) {
      const int idx = r * 512 + tid;
      const int t  = idx >> 2;
      const int mc = (idx & 3) << 3;
      const float* src = Vg + (size_t)(b * T_ + t) * M_ + m0 + mc;
      const float4 f0 = *reinterpret_cast<const float4*>(src);
      const float4 f1 = *reinterpret_cast<const float4*>(src + 4);
      f16x8 v8;
      v8[0] = (f16)f0.x; v8[1] = (f16)f0.y; v8[2] = (f16)f0.z; v8[3] = (f16)f0.w;
      v8[4] = (f16)f1.x; v8[5] = (f16)f1.y; v8[6] = (f16)f1.z; v8[7] = (f16)f1.w;
      *reinterpret_cast<f16x8*>(&Vsf[t * KVB + (mc ^ ((t & 3) << 3))]) = v8;
    }
    __syncthreads();
    f32x4 sacc = f32x4{0.f, 0.f, 0.f, 0.f};
    {
      const int abase = (ms * 16 + l15) * KSTR + lq * 8;
      #pragma unroll
      for (int ks = 0; ks < 16; ++ks) {
        const f16x8 a = *reinterpret_cast<const f16x8*>(&Ksf[abase + ks * 32]);
        sacc = __builtin_amdgcn_mfma_f32_16x16x32_f16(a, qh[ks], sacc, 0, 0, 0);
        sacc = __builtin_amdgcn_mfma_f32_16x16x32_f16(a, ql[ks], sacc, 0, 0, 0);
      }
    }
    const int n = ng * 16 + l15;
    float tmax = fmaxf(fmaxf(sacc[0], sacc[1]), fmaxf(sacc[2], sacc[3]));
    tmax = fmaxf(tmax, __shfl_xor(tmax, 16));
    tmax = fmaxf(tmax, __shfl_xor(tmax, 32));
    if (lane < 16) redmax[ms][ng * 16 + lane] = tmax;
    __syncthreads();
    const float gmax = fmaxf(redmax[0][n], redmax[1][n]);
    const float mnew = fmaxf(m_run, gmax);
    const float alpha = __expf(m_run - mnew);
    if (ms == 0 && lane < 16) stat_al[ng * 16 + lane] = alpha;
    const float p0 = __expf(sacc[0] - mnew);
    const float p1 = __expf(sacc[1] - mnew);
    const float p2 = __expf(sacc[2] - mnew);
    const float p3 = __expf(sacc[3] - mnew);
    float psum = (p0 + p1) + (p2 + p3);
    psum += __shfl_xor(psum, 16);
    psum += __shfl_xor(psum, 32);
    if (lane < 16) redsum[ms][ng * 16 + lane] = psum;
    {
      f16x4 pw;
      pw[0] = (f16)p0; pw[1] = (f16)p1; pw[2] = (f16)p2; pw[3] = (f16)p3;
      *reinterpret_cast<f16x4*>(&Psf[n * PSTRF + ms * 16 + lq * 4]) = pw;
    }
    __syncthreads();
    l_run = l_run * alpha + redsum[0][n] + redsum[1][n];
    m_run = mnew;
    #pragma unroll
    for (int nf = 0; nf < 4; ++nf) {
      const float av = stat_al[nf * 16 + l15];
      #pragma unroll
      for (int tf = 0; tf < 4; ++tf) {
        oacc[tf][nf][0] *= av; oacc[tf][nf][1] *= av;
        oacc[tf][nf][2] *= av; oacc[tf][nf][3] *= av;
      }
    }
    {
      f16x8 vfr[4];
      #pragma unroll
      for (int tf = 0; tf < 4; ++tf) {
        const int t = w * 64 + tf * 16 + l15;
        vfr[tf] = *reinterpret_cast<const f16x8*>(&Vsf[t * KVB + ((lq * 8) ^ ((t & 3) << 3))]);
      }
      #pragma unroll
      for (int nf = 0; nf < 4; ++nf) {
        const f16x8 pfr = *reinterpret_cast<const f16x8*>(&Psf[(nf * 16 + l15) * PSTRF + lq * 8]);
        #pragma unroll
        for (int tf = 0; tf < 4; ++tf)
          oacc[tf][nf] = __builtin_amdgcn_mfma_f32_16x16x32_f16(vfr[tf], pfr, oacc[tf][nf], 0, 0, 0);
      }
    }
    __syncthreads();
  }
  if (ms == 0 && lane < 16) stat_il[ng * 16 + lane] = 1.0f / l_run;
  __syncthreads();
  #pragma unroll
  for (int nf = 0; nf < 4; ++nf) {
    const float il = stat_il[nf * 16 + l15];
    const size_t base = (size_t)(b * N_ + nb + nf * 16 + l15) * T_;
    #pragma unroll
    for (int tf = 0; tf < 4; ++tf) {
      const int t = w * 64 + tf * 16 + lq * 4;
      float4 o;
      o.x = oacc[tf][nf][0] * il;
      o.y = oacc[tf][nf][1] * il;
      o.z = oacc[tf][nf][2] * il;
      o.w = oacc[tf][nf][3] * il;
      *reinterpret_cast<float4*>(Og + base + t) = o;
    }
  }
}

extern "C" void kernel_launch(void* const* d_in, const int* in_sizes, int n_in,
                              void* d_out, int out_size, void* d_ws, size_t ws_size,
                              hipStream_t stream) {
  const float* Q = (const float*)d_in[0];
  const float* K = (const float*)d_in[1];
  const float* V = (const float*)d_in[2];
  float* O = (float*)d_out;
  (void)in_sizes; (void)n_in; (void)out_size;

  const size_t needed = (size_t)B_ * NT * KT_F16 * 2 * 2;  // pk + pv = 64MB
  if (ws_size >= needed) {
    f16* pk = (f16*)d_ws;
    f16* pv = pk + (size_t)B_ * NT * KT_F16;
    pack_k<<<dim3(B_ * NT * 8), dim3(256), 0, stream>>>(K, pk);
    pack_v<<<dim3(B_ * NT), dim3(256), 0, stream>>>(V, pv);
    fattn<<<dim3(B_ * (N_ / NBLK)), dim3(512), 0, stream>>>(Q, pk, pv, O);
  } else {
    fattn_fb<<<dim3(B_ * (N_ / NBLK)), dim3(512), 0, stream>>>(Q, K, V, O);
  }
}

// Round 12
// 440.597 us; speedup vs baseline: 1.8446x; 1.8446x over previous
//
#include <hip/hip_runtime.h>
#include <hip/hip_bf16.h>
#include <stdint.h>

#define B_ 8
#define N_ 4096
#define T_ 512
#define M_ 4096
#define KVB 32
#define NBLK 64
#define NT 128            // 32-m tiles
#define KT_F16 (KVB*T_)   // 16384 f16 = 32KB per packed K tile
#define VT_F16 (T_*KVB)   // 16384 f16 = 32KB per packed V tile

typedef _Float16 f16;
typedef __attribute__((ext_vector_type(8))) f16 f16x8;
typedef __attribute__((ext_vector_type(4))) f16 f16x4;
typedef __attribute__((ext_vector_type(4))) float f32x4;

__device__ __forceinline__ void gld16(const void* g, void* l) {
  __builtin_amdgcn_global_load_lds(
      (const __attribute__((address_space(1))) unsigned int*)g,
      (__attribute__((address_space(3))) unsigned int*)l, 16, 0, 0);
}

// ---------------- pack kernels (identical to R3..R11, proven) ----------------
__global__ __launch_bounds__(256) void pack_k(const float* __restrict__ Kg,
                                              f16* __restrict__ pk) {
  const int bx = blockIdx.x;
  const int ts = bx & 7;
  const int mt = (bx >> 3) & (NT - 1);
  const int b  = bx >> 10;
  const int m0 = mt * KVB;
  const int tid = threadIdx.x;
  __shared__ float tileT[64][33];
  {
    const int tl = tid >> 2;
    const int mseg = (tid & 3) * 8;
    const float* src = Kg + (size_t)(b * T_ + ts * 64 + tl) * M_ + m0 + mseg;
    const float4 a = *reinterpret_cast<const float4*>(src);
    const float4 c = *reinterpret_cast<const float4*>(src + 4);
    tileT[tl][mseg + 0] = a.x; tileT[tl][mseg + 1] = a.y;
    tileT[tl][mseg + 2] = a.z; tileT[tl][mseg + 3] = a.w;
    tileT[tl][mseg + 4] = c.x; tileT[tl][mseg + 5] = c.y;
    tileT[tl][mseg + 6] = c.z; tileT[tl][mseg + 7] = c.w;
  }
  __syncthreads();
  {
    const int m  = tid >> 3;
    const int jl = tid & 7;
    const int tlc = (jl ^ (m & 7)) * 8;
    f16x8 o;
    #pragma unroll
    for (int i = 0; i < 8; ++i) o[i] = (f16)tileT[tlc + i][m];
    f16* dst = pk + ((size_t)(b * NT + mt) * KVB + m) * T_ + (ts * 8 + jl) * 8;
    *reinterpret_cast<f16x8*>(dst) = o;
  }
}

__global__ __launch_bounds__(256) void pack_v(const float* __restrict__ Vg,
                                              f16* __restrict__ pv) {
  const int bx = blockIdx.x;        // b*NT + mt
  const int mt = bx & (NT - 1);
  const int b  = bx >> 7;
  const int m0 = mt * KVB;
  const int tid = threadIdx.x;
  #pragma unroll
  for (int it = 0; it < 8; ++it) {
    const int task = it * 256 + tid;      // 0..2047
    const int ts = task >> 6;
    const int ln = task & 63;
    const int t  = ts * 16 + (ln & 15);
    const int mc = (ln >> 4) * 8;
    const float* src = Vg + (size_t)(b * T_ + t) * M_ + m0 + mc;
    const float4 a = *reinterpret_cast<const float4*>(src);
    const float4 d = *reinterpret_cast<const float4*>(src + 4);
    f16x8 o;
    o[0] = (f16)a.x; o[1] = (f16)a.y; o[2] = (f16)a.z; o[3] = (f16)a.w;
    o[4] = (f16)d.x; o[5] = (f16)d.y; o[6] = (f16)d.z; o[7] = (f16)d.w;
    *reinterpret_cast<f16x8*>(pv + ((size_t)bx * 2048 + task) * 8) = o;
  }
}

// ------- main: producer-consumer. waves 0-3 = S/softmax, waves 4-7 = PV -------
// PV loop 2x-unrolled: vfrA/vfrB statically indexed (rule-#20 fix vs R11).
__global__ __launch_bounds__(512, 2) void fattn(
    const float* __restrict__ Qg, const f16* __restrict__ pk,
    const f16* __restrict__ pv, float* __restrict__ Og)
{
  __shared__ __align__(16) f16 Ks[2][KT_F16];    // 64KB dbuf
  __shared__ __align__(16) f16 Ps[2][NBLK * 32]; // 2 x 4KB: [n][m], 64B rows, chunk-XOR
  __shared__ float redmax[2][NBLK];
  __shared__ float redsum[2][NBLK];
  __shared__ float stat_al[2][NBLK];
  __shared__ float stat_il[NBLK];

  const int raw = blockIdx.x;
  const int bid = (raw & 7) * 64 + (raw >> 3);   // XCD <-> batch (L2 locality)
  const int b   = bid >> 6;
  const int nb  = (bid & 63) << 6;
  const int tid  = threadIdx.x;
  const int wv   = tid >> 6;
  const int lane = tid & 63;
  const int l15  = lane & 15;
  const int lq   = lane >> 4;

  const char* kbase = (const char*)(pk + (size_t)b * NT * KT_F16);
  const f16*  pvb   = pv + (size_t)b * NT * VT_F16;
  const int lo = wv * 4096;                      // per-wave 4KB slice of a 32KB tile

  // prologue: all 8 waves stage K tile 0 -> buf0
  #pragma unroll
  for (int r = 0; r < 4; ++r)
    gld16(kbase + lo + r * 1024 + lane * 16, (char*)&Ks[0][0] + lo + r * 1024 + lane * 16);

  if (wv < 4) {
    // ================== S-GROUP: wave = (nh = wv>>1, mh = wv&1) ==================
    const int nh = wv >> 1;       // 32-n half
    const int mh = wv & 1;        // 16-m half of the 32-m tile
    const int n0 = nh * 32 + l15;
    const int n1 = n0 + 16;

    // Q fragments: two 16-n sets, fp16 (validated numerics: absmax 0.047 < 0.1025)
    f16x8 qh0[16], qh1[16];
    {
      const float* qrow0 = Qg + (size_t)(b * N_ + nb + nh * 32 + l15) * T_;
      const float* qrow1 = qrow0 + (size_t)16 * T_;
      #pragma unroll
      for (int ks = 0; ks < 16; ++ks) {
        const int k0 = ks * 32 + lq * 8;
        float f[8];
        *reinterpret_cast<float4*>(&f[0]) = *reinterpret_cast<const float4*>(qrow0 + k0);
        *reinterpret_cast<float4*>(&f[4]) = *reinterpret_cast<const float4*>(qrow0 + k0 + 4);
        f16x8 h;
        #pragma unroll
        for (int j = 0; j < 8; ++j) h[j] = (f16)f[j];
        qh0[ks] = h;
        *reinterpret_cast<float4*>(&f[0]) = *reinterpret_cast<const float4*>(qrow1 + k0);
        *reinterpret_cast<float4*>(&f[4]) = *reinterpret_cast<const float4*>(qrow1 + k0 + 4);
        #pragma unroll
        for (int j = 0; j < 8; ++j) h[j] = (f16)f[j];
        qh1[ks] = h;
      }
    }

    float m_run0 = -INFINITY, m_run1 = -INFINITY;
    float l_par0 = 0.f, l_par1 = 0.f;   // per-lane partial (n, lq-quarter of m)

    const int mrow = mh * 16 + l15;     // row in [0,32)
    const int mb = mrow * T_;
    const int mx = l15 & 7;

    __syncthreads();   // K0 resident

    for (int dt = 0; dt < NT; ++dt) {
      const int cur = dt & 1;
      if (dt + 1 < NT) {
        const char* kt = kbase + (size_t)(dt + 1) * (KT_F16 * 2);
        char* kd = (char*)&Ks[cur ^ 1][0];
        #pragma unroll
        for (int r = 0; r < 4; ++r)
          gld16(kt + lo + r * 1024 + lane * 16, kd + lo + r * 1024 + lane * 16);
      }

      // phase1: S^T — ONE A-read feeds both n-subgroups
      f32x4 s0 = f32x4{0.f, 0.f, 0.f, 0.f};
      f32x4 s1 = f32x4{0.f, 0.f, 0.f, 0.f};
      {
        const f16* KsC = &Ks[cur][0];
        __builtin_amdgcn_s_setprio(1);
        #pragma unroll
        for (int ks = 0; ks < 16; ++ks) {
          const int c = ((ks << 2) + lq) ^ mx;
          const f16x8 a = *reinterpret_cast<const f16x8*>(KsC + mb + c * 8);
          s0 = __builtin_amdgcn_mfma_f32_16x16x32_f16(a, qh0[ks], s0, 0, 0, 0);
          s1 = __builtin_amdgcn_mfma_f32_16x16x32_f16(a, qh1[ks], s1, 0, 0, 0);
        }
        __builtin_amdgcn_s_setprio(0);
      }
      float t0 = fmaxf(fmaxf(s0[0], s0[1]), fmaxf(s0[2], s0[3]));
      float t1 = fmaxf(fmaxf(s1[0], s1[1]), fmaxf(s1[2], s1[3]));
      t0 = fmaxf(t0, __shfl_xor(t0, 16)); t0 = fmaxf(t0, __shfl_xor(t0, 32));
      t1 = fmaxf(t1, __shfl_xor(t1, 16)); t1 = fmaxf(t1, __shfl_xor(t1, 32));
      if (lane < 16) {
        redmax[mh][nh * 32 + lane] = t0;
        redmax[mh][nh * 32 + 16 + lane] = t1;
      }
      asm volatile("s_waitcnt lgkmcnt(0)" ::: "memory");
      __builtin_amdgcn_s_barrier();                      // B1
      __builtin_amdgcn_sched_barrier(0);

      // phase2: softmax (PV-group is doing PV(dt-1) concurrently)
      const float g0 = fmaxf(redmax[0][n0], redmax[1][n0]);
      const float g1 = fmaxf(redmax[0][n1], redmax[1][n1]);
      const float mnew0 = fmaxf(m_run0, g0);
      const float mnew1 = fmaxf(m_run1, g1);
      const float alpha0 = __expf(m_run0 - mnew0);       // first tile: 0
      const float alpha1 = __expf(m_run1 - mnew1);
      if (mh == 0 && lane < 16) {
        stat_al[cur][nh * 32 + lane] = alpha0;
        stat_al[cur][nh * 32 + 16 + lane] = alpha1;
      }
      const float e00 = __expf(s0[0] - mnew0);
      const float e01 = __expf(s0[1] - mnew0);
      const float e02 = __expf(s0[2] - mnew0);
      const float e03 = __expf(s0[3] - mnew0);
      const float e10 = __expf(s1[0] - mnew1);
      const float e11 = __expf(s1[1] - mnew1);
      const float e12 = __expf(s1[2] - mnew1);
      const float e13 = __expf(s1[3] - mnew1);
      l_par0 = l_par0 * alpha0 + ((e00 + e01) + (e02 + e03));
      l_par1 = l_par1 * alpha1 + ((e10 + e11) + (e12 + e13));
      m_run0 = mnew0; m_run1 = mnew1;
      {
        f16x4 w0, w1;
        w0[0] = (f16)e00; w0[1] = (f16)e01; w0[2] = (f16)e02; w0[3] = (f16)e03;
        w1[0] = (f16)e10; w1[1] = (f16)e11; w1[2] = (f16)e12; w1[3] = (f16)e13;
        const int ch = mh * 2 + (lq >> 1);
        const int e = (lq & 1) * 4;
        *reinterpret_cast<f16x4*>(&Ps[cur][n0 * 32 + ((ch ^ ((n0 >> 1) & 3)) * 8) + e]) = w0;
        *reinterpret_cast<f16x4*>(&Ps[cur][n1 * 32 + ((ch ^ ((n1 >> 1) & 3)) * 8) + e]) = w1;
      }
      asm volatile("s_waitcnt lgkmcnt(0) vmcnt(0)" ::: "memory");
      __builtin_amdgcn_s_barrier();                      // EB
      __builtin_amdgcn_sched_barrier(0);
    }

    // epilogue: reduce l over lq, publish 1/l
    l_par0 += __shfl_xor(l_par0, 16); l_par0 += __shfl_xor(l_par0, 32);
    l_par1 += __shfl_xor(l_par1, 16); l_par1 += __shfl_xor(l_par1, 32);
    if (lane < 16) {
      redsum[mh][nh * 32 + lane] = l_par0;
      redsum[mh][nh * 32 + 16 + lane] = l_par1;
    }
    __syncthreads();   // X1
    if (mh == 0 && lane < 16) {
      const int na = nh * 32 + lane;
      const int nbq = na + 16;
      stat_il[na] = 1.0f / (redsum[0][na] + redsum[1][na]);
      stat_il[nbq] = 1.0f / (redsum[0][nbq] + redsum[1][nbq]);
    }
    __syncthreads();   // X2
  } else {
    // ============ PV-GROUP: wave owns t in [(wv-4)*128, +128); 2x-unrolled ============
    const int pw = wv - 4;
    const int tb = pw * 128;

    f32x4 oacc[8][4];
    #pragma unroll
    for (int tf = 0; tf < 8; ++tf)
      #pragma unroll
      for (int nf = 0; nf < 4; ++nf)
        oacc[tf][nf] = f32x4{0.f, 0.f, 0.f, 0.f};
    f16x8 vfrA[8], vfrB[8];   // STATIC names (rule-#20 fix)

    __syncthreads();   // K0 resident

    for (int dt = 0; dt < NT; dt += 2) {
      // ======== even tile dt: cur=0, prv=1 ========
      {
        // stage K(dt+1) -> buf1 (dt+1 <= 127 always)
        const char* kt = kbase + (size_t)(dt + 1) * (KT_F16 * 2);
        char* kd = (char*)&Ks[1][0];
        #pragma unroll
        for (int r = 0; r < 4; ++r)
          gld16(kt + lo + r * 1024 + lane * 16, kd + lo + r * 1024 + lane * 16);
        // V(dt) -> vfrA
        const f16* vt = pvb + (size_t)dt * 2048 * 8;
        #pragma unroll
        for (int tf = 0; tf < 8; ++tf)
          vfrA[tf] = *reinterpret_cast<const f16x8*>(
              vt + ((size_t)(pw * 8 + tf) * 64 + lane) * 8);
        if (dt > 0) {
          const float al0 = stat_al[1][l15];
          const float al1 = stat_al[1][16 + l15];
          const float al2 = stat_al[1][32 + l15];
          const float al3 = stat_al[1][48 + l15];
          if (__any((al0 != 1.0f) || (al1 != 1.0f) || (al2 != 1.0f) || (al3 != 1.0f))) {
            #pragma unroll
            for (int nf = 0; nf < 4; ++nf) {
              const float av = nf == 0 ? al0 : (nf == 1 ? al1 : (nf == 2 ? al2 : al3));
              #pragma unroll
              for (int tf = 0; tf < 8; ++tf) {
                oacc[tf][nf][0] *= av; oacc[tf][nf][1] *= av;
                oacc[tf][nf][2] *= av; oacc[tf][nf][3] *= av;
              }
            }
          }
        }
        __builtin_amdgcn_s_barrier();                    // B1
        __builtin_amdgcn_sched_barrier(0);
        if (dt > 0) {   // PV(dt-1): Ps[1], vfrB
          __builtin_amdgcn_s_setprio(1);
          #pragma unroll
          for (int nf = 0; nf < 4; ++nf) {
            const int n2 = nf * 16 + l15;
            const f16x8 pfr = *reinterpret_cast<const f16x8*>(
                &Ps[1][n2 * 32 + (lq ^ ((n2 >> 1) & 3)) * 8]);
            #pragma unroll
            for (int tf = 0; tf < 8; ++tf)
              oacc[tf][nf] = __builtin_amdgcn_mfma_f32_16x16x32_f16(vfrB[tf], pfr, oacc[tf][nf], 0, 0, 0);
          }
          __builtin_amdgcn_s_setprio(0);
        }
        asm volatile("s_waitcnt vmcnt(8)" ::: "memory"); // drain K(dt+1); V(dt) stays
        __builtin_amdgcn_s_barrier();                    // EB
        __builtin_amdgcn_sched_barrier(0);
      }
      // ======== odd tile dt+1: cur=1, prv=0 ========
      {
        if (dt + 2 < NT) {
          const char* kt = kbase + (size_t)(dt + 2) * (KT_F16 * 2);
          char* kd = (char*)&Ks[0][0];
          #pragma unroll
          for (int r = 0; r < 4; ++r)
            gld16(kt + lo + r * 1024 + lane * 16, kd + lo + r * 1024 + lane * 16);
        }
        // V(dt+1) -> vfrB
        const f16* vt = pvb + (size_t)(dt + 1) * 2048 * 8;
        #pragma unroll
        for (int tf = 0; tf < 8; ++tf)
          vfrB[tf] = *reinterpret_cast<const f16x8*>(
              vt + ((size_t)(pw * 8 + tf) * 64 + lane) * 8);
        {
          const float al0 = stat_al[0][l15];
          const float al1 = stat_al[0][16 + l15];
          const float al2 = stat_al[0][32 + l15];
          const float al3 = stat_al[0][48 + l15];
          if (__any((al0 != 1.0f) || (al1 != 1.0f) || (al2 != 1.0f) || (al3 != 1.0f))) {
            #pragma unroll
            for (int nf = 0; nf < 4; ++nf) {
              const float av = nf == 0 ? al0 : (nf == 1 ? al1 : (nf == 2 ? al2 : al3));
              #pragma unroll
              for (int tf = 0; tf < 8; ++tf) {
                oacc[tf][nf][0] *= av; oacc[tf][nf][1] *= av;
                oacc[tf][nf][2] *= av; oacc[tf][nf][3] *= av;
              }
            }
          }
        }
        __builtin_amdgcn_s_barrier();                    // B1
        __builtin_amdgcn_sched_barrier(0);
        {   // PV(dt): Ps[0], vfrA
          __builtin_amdgcn_s_setprio(1);
          #pragma unroll
          for (int nf = 0; nf < 4; ++nf) {
            const int n2 = nf * 16 + l15;
            const f16x8 pfr = *reinterpret_cast<const f16x8*>(
                &Ps[0][n2 * 32 + (lq ^ ((n2 >> 1) & 3)) * 8]);
            #pragma unroll
            for (int tf = 0; tf < 8; ++tf)
              oacc[tf][nf] = __builtin_amdgcn_mfma_f32_16x16x32_f16(vfrA[tf], pfr, oacc[tf][nf], 0, 0, 0);
          }
          __builtin_amdgcn_s_setprio(0);
        }
        asm volatile("s_waitcnt vmcnt(8)" ::: "memory"); // drain K(dt+2); V(dt+1) stays
        __builtin_amdgcn_s_barrier();                    // EB
        __builtin_amdgcn_sched_barrier(0);
      }
    }

    // epilogue: final PV(NT-1) = odd tile -> Ps[1], vfrB
    {
      const float al0 = stat_al[1][l15];
      const float al1 = stat_al[1][16 + l15];
      const float al2 = stat_al[1][32 + l15];
      const float al3 = stat_al[1][48 + l15];
      if (__any((al0 != 1.0f) || (al1 != 1.0f) || (al2 != 1.0f) || (al3 != 1.0f))) {
        #pragma unroll
        for (int nf = 0; nf < 4; ++nf) {
          const float av = nf == 0 ? al0 : (nf == 1 ? al1 : (nf == 2 ? al2 : al3));
          #pragma unroll
          for (int tf = 0; tf < 8; ++tf) {
            oacc[tf][nf][0] *= av; oacc[tf][nf][1] *= av;
            oacc[tf][nf][2] *= av; oacc[tf][nf][3] *= av;
          }
        }
      }
      #pragma unroll
      for (int nf = 0; nf < 4; ++nf) {
        const int n2 = nf * 16 + l15;
        const f16x8 pfr = *reinterpret_cast<const f16x8*>(
            &Ps[1][n2 * 32 + (lq ^ ((n2 >> 1) & 3)) * 8]);
        #pragma unroll
        for (int tf = 0; tf < 8; ++tf)
          oacc[tf][nf] = __builtin_amdgcn_mfma_f32_16x16x32_f16(vfrB[tf], pfr, oacc[tf][nf], 0, 0, 0);
      }
    }
    __syncthreads();   // X1 (match S-group)
    __syncthreads();   // X2 (stat_il committed)
    #pragma unroll
    for (int nf = 0; nf < 4; ++nf) {
      const float il = stat_il[nf * 16 + l15];
      const size_t base = (size_t)(b * N_ + nb + nf * 16 + l15) * T_;
      #pragma unroll
      for (int tf = 0; tf < 8; ++tf) {
        const int t = tb + tf * 16 + lq * 4;
        float4 o;
        o.x = oacc[tf][nf][0] * il;
        o.y = oacc[tf][nf][1] * il;
        o.z = oacc[tf][nf][2] * il;
        o.w = oacc[tf][nf][3] * il;
        *reinterpret_cast<float4*>(Og + base + t) = o;
      }
    }
  }
}

// ---------------- fallback (R2-proven, no ws): 8-wave 64-n block ----------------
#define KSTR 520
#define PSTRF 48
__global__ __launch_bounds__(512, 2) void fattn_fb(
    const float* __restrict__ Qg, const float* __restrict__ Kg,
    const float* __restrict__ Vg, float* __restrict__ Og)
{
  __shared__ __align__(16) f16 Ksf[KVB * KSTR];
  __shared__ __align__(16) f16 Vsf[T_ * KVB];
  __shared__ __align__(16) f16 Psf[64 * PSTRF];
  __shared__ float redmax[2][64];
  __shared__ float redsum[2][64];
  __shared__ float stat_al[64];
  __shared__ float stat_il[64];

  const int bid  = blockIdx.x;
  const int b    = bid >> 6;
  const int nb   = (bid & 63) << 6;
  const int tid  = threadIdx.x;
  const int w    = tid >> 6;
  const int lane = tid & 63;
  const int l15  = lane & 15;
  const int lq   = lane >> 4;
  const int ms   = w & 1;
  const int ng   = w >> 1;

  f16x8 qh[16], ql[16];
  {
    const float* qrow = Qg + (size_t)(b * N_ + nb + ng * 16 + l15) * T_;
    #pragma unroll
    for (int ks = 0; ks < 16; ++ks) {
      const int k0 = ks * 32 + lq * 8;
      float f[8];
      *reinterpret_cast<float4*>(&f[0]) = *reinterpret_cast<const float4*>(qrow + k0);
      *reinterpret_cast<float4*>(&f[4]) = *reinterpret_cast<const float4*>(qrow + k0 + 4);
      f16x8 h, l;
      #pragma unroll
      for (int j = 0; j < 8; ++j) { h[j] = (f16)f[j]; l[j] = (f16)(f[j] - (float)h[j]); }
      qh[ks] = h; ql[ks] = l;
    }
  }
  f32x4 oacc[4][4];
  #pragma unroll
  for (int tf = 0; tf < 4; ++tf)
    #pragma unroll
    for (int nf = 0; nf < 4; ++nf)
      oacc[tf][nf] = f32x4{0.f, 0.f, 0.f, 0.f};
  float m_run = -INFINITY, l_run = 0.f;

  for (int mt = 0; mt < M_ / KVB; ++mt) {
    const int m0 = mt * KVB;
    #pragma unroll
    for (int r = 0; r < 8; ++r) {
      const int task = r * 512 + tid;
      const int m  = task & 31;
      const int t0 = (task >> 5) << 2;
      const float* src = Kg + (size_t)(b * T_ + t0) * M_ + m0 + m;
      f16x4 kk;
      kk[0] = (f16)src[0]; kk[1] = (f16)src[M_];
      kk[2] = (f16)src[2 * M_]; kk[3] = (f16)src[3 * M_];
      *reinterpret_cast<f16x4*>(&Ksf[m * KSTR + t0]) = kk;
    }
    #pragma unroll
    for (int r = 0; r < 4; ++r) {
      const int idx = r * 512 + tid;
      const int t  = idx >> 2;
      const int mc = (idx & 3) << 3;
      const float* src = Vg + (size_t)(b * T_ + t) * M_ + m0 + mc;
      const float4 f0 = *reinterpret_cast<const float4*>(src);
      const float4 f1 = *reinterpret_cast<const float4*>(src + 4);
      f16x8 v8;
      v8[0] = (f16)f0.x; v8[1] = (f16)f0.y; v8[2] = (f16)f0.z; v8[3] = (f16)f0.w;
      v8[4] = (f16)f1.x; v8[5] = (f16)f1.y; v8[6] = (f16)f1.z; v8[7] = (f16)f1.w;
      *reinterpret_cast<f16x8*>(&Vsf[t * KVB + (mc ^ ((t & 3) << 3))]) = v8;
    }
    __syncthreads();
    f32x4 sacc = f32x4{0.f, 0.f, 0.f, 0.f};
    {
      const int abase = (ms * 16 + l15) * KSTR + lq * 8;
      #pragma unroll
      for (int ks = 0; ks < 16; ++ks) {
        const f16x8 a = *reinterpret_cast<const f16x8*>(&Ksf[abase + ks * 32]);
        sacc = __builtin_amdgcn_mfma_f32_16x16x32_f16(a, qh[ks], sacc, 0, 0, 0);
        sacc = __builtin_amdgcn_mfma_f32_16x16x32_f16(a, ql[ks], sacc, 0, 0, 0);
      }
    }
    const int n = ng * 16 + l15;
    float tmax = fmaxf(fmaxf(sacc[0], sacc[1]), fmaxf(sacc[2], sacc[3]));
    tmax = fmaxf(tmax, __shfl_xor(tmax, 16));
    tmax = fmaxf(tmax, __shfl_xor(tmax, 32));
    if (lane < 16) redmax[ms][ng * 16 + lane] = tmax;
    __syncthreads();
    const float gmax = fmaxf(redmax[0][n], redmax[1][n]);
    const float mnew = fmaxf(m_run, gmax);
    const float alpha = __expf(m_run - mnew);
    if (ms == 0 && lane < 16) stat_al[ng * 16 + lane] = alpha;
    const float p0 = __expf(sacc[0] - mnew);
    const float p1 = __expf(sacc[1] - mnew);
    const float p2 = __expf(sacc[2] - mnew);
    const float p3 = __expf(sacc[3] - mnew);
    float psum = (p0 + p1) + (p2 + p3);
    psum += __shfl_xor(psum, 16);
    psum += __shfl_xor(psum, 32);
    if (lane < 16) redsum[ms][ng * 16 + lane] = psum;
    {
      f16x4 pw;
      pw[0] = (f16)p0; pw[1] = (f16)p1; pw[2] = (f16)p2; pw[3] = (f16)p3;
      *reinterpret_cast<f16x4*>(&Psf[n * PSTRF + ms * 16 + lq * 4]) = pw;
    }
    __syncthreads();
    l_run = l_run * alpha + redsum[0][n] + redsum[1][n];
    m_run = mnew;
    #pragma unroll
    for (int nf = 0; nf < 4; ++nf) {
      const float av = stat_al[nf * 16 + l15];
      #pragma unroll
      for (int tf = 0; tf < 4; ++tf) {
        oacc[tf][nf][0] *= av; oacc[tf][nf][1] *= av;
        oacc[tf][nf][2] *= av; oacc[tf][nf][3] *= av;
      }
    }
    {
      f16x8 vfr[4];
      #pragma unroll
      for (int tf = 0; tf < 4; ++tf) {
        const int t = w * 64 + tf * 16 + l15;
        vfr[tf] = *reinterpret_cast<const f16x8*>(&Vsf[t * KVB + ((lq * 8) ^ ((t & 3) << 3))]);
      }
      #pragma unroll
      for (int nf = 0; nf < 4; ++nf) {
        const f16x8 pfr = *reinterpret_cast<const f16x8*>(&Psf[(nf * 16 + l15) * PSTRF + lq * 8]);
        #pragma unroll
        for (int tf = 0; tf < 4; ++tf)
          oacc[tf][nf] = __builtin_amdgcn_mfma_f32_16x16x32_f16(vfr[tf], pfr, oacc[tf][nf], 0, 0, 0);
      }
    }
    __syncthreads();
  }
  if (ms == 0 && lane < 16) stat_il[ng * 16 + lane] = 1.0f / l_run;
  __syncthreads();
  #pragma unroll
  for (int nf = 0; nf < 4; ++nf) {
    const float il = stat_il[nf * 16 + l15];
    const size_t base = (size_t)(b * N_ + nb + nf * 16 + l15) * T_;
    #pragma unroll
    for (int tf = 0; tf < 4; ++tf) {
      const int t = w * 64 + tf * 16 + lq * 4;
      float4 o;
      o.x = oacc[tf][nf][0] * il;
      o.y = oacc[tf][nf][1] * il;
      o.z = oacc[tf][nf][2] * il;
      o.w = oacc[tf][nf][3] * il;
      *reinterpret_cast<float4*>(Og + base + t) = o;
    }
  }
}

extern "C" void kernel_launch(void* const* d_in, const int* in_sizes, int n_in,
                              void* d_out, int out_size, void* d_ws, size_t ws_size,
                              hipStream_t stream) {
  const float* Q = (const float*)d_in[0];
  const float* K = (const float*)d_in[1];
  const float* V = (const float*)d_in[2];
  float* O = (float*)d_out;
  (void)in_sizes; (void)n_in; (void)out_size;

  const size_t needed = (size_t)B_ * NT * KT_F16 * 2 * 2;  // pk + pv = 64MB
  if (ws_size >= needed) {
    f16* pk = (f16*)d_ws;
    f16* pv = pk + (size_t)B_ * NT * KT_F16;
    pack_k<<<dim3(B_ * NT * 8), dim3(256), 0, stream>>>(K, pk);
    pack_v<<<dim3(B_ * NT), dim3(256), 0, stream>>>(V, pv);
    fattn<<<dim3(B_ * (N_ / NBLK)), dim3(512), 0, stream>>>(Q, pk, pv, O);
  } else {
    fattn_fb<<<dim3(B_ * (N_ / NBLK)), dim3(512), 0, stream>>>(Q, K, V, O);
  }
}

// Round 13
// 430.360 us; speedup vs baseline: 1.8885x; 1.0238x over previous
//
#include <hip/hip_runtime.h>
#include <hip/hip_bf16.h>
#include <stdint.h>

#define B_ 8
#define N_ 4096
#define T_ 512
#define M_ 4096
#define KVB 32
#define NBLK 64
#define NT 128            // 32-m tiles
#define KT_F16 (KVB*T_)   // 16384 f16 = 32KB per packed K tile
#define VT_F16 (T_*KVB)   // 16384 f16 = 32KB per packed V tile

typedef _Float16 f16;
typedef __attribute__((ext_vector_type(8))) f16 f16x8;
typedef __attribute__((ext_vector_type(4))) f16 f16x4;
typedef __attribute__((ext_vector_type(4))) float f32x4;

__device__ __forceinline__ void gld16(const void* g, void* l) {
  __builtin_amdgcn_global_load_lds(
      (const __attribute__((address_space(1))) unsigned int*)g,
      (__attribute__((address_space(3))) unsigned int*)l, 16, 0, 0);
}

// ---------------- pack kernels (identical to R3..R12, proven) ----------------
__global__ __launch_bounds__(256) void pack_k(const float* __restrict__ Kg,
                                              f16* __restrict__ pk) {
  const int bx = blockIdx.x;
  const int ts = bx & 7;
  const int mt = (bx >> 3) & (NT - 1);
  const int b  = bx >> 10;
  const int m0 = mt * KVB;
  const int tid = threadIdx.x;
  __shared__ float tileT[64][33];
  {
    const int tl = tid >> 2;
    const int mseg = (tid & 3) * 8;
    const float* src = Kg + (size_t)(b * T_ + ts * 64 + tl) * M_ + m0 + mseg;
    const float4 a = *reinterpret_cast<const float4*>(src);
    const float4 c = *reinterpret_cast<const float4*>(src + 4);
    tileT[tl][mseg + 0] = a.x; tileT[tl][mseg + 1] = a.y;
    tileT[tl][mseg + 2] = a.z; tileT[tl][mseg + 3] = a.w;
    tileT[tl][mseg + 4] = c.x; tileT[tl][mseg + 5] = c.y;
    tileT[tl][mseg + 6] = c.z; tileT[tl][mseg + 7] = c.w;
  }
  __syncthreads();
  {
    const int m  = tid >> 3;
    const int jl = tid & 7;
    const int tlc = (jl ^ (m & 7)) * 8;
    f16x8 o;
    #pragma unroll
    for (int i = 0; i < 8; ++i) o[i] = (f16)tileT[tlc + i][m];
    f16* dst = pk + ((size_t)(b * NT + mt) * KVB + m) * T_ + (ts * 8 + jl) * 8;
    *reinterpret_cast<f16x8*>(dst) = o;
  }
}

__global__ __launch_bounds__(256) void pack_v(const float* __restrict__ Vg,
                                              f16* __restrict__ pv) {
  const int bx = blockIdx.x;        // b*NT + mt
  const int mt = bx & (NT - 1);
  const int b  = bx >> 7;
  const int m0 = mt * KVB;
  const int tid = threadIdx.x;
  #pragma unroll
  for (int it = 0; it < 8; ++it) {
    const int task = it * 256 + tid;      // 0..2047
    const int ts = task >> 6;
    const int ln = task & 63;
    const int t  = ts * 16 + (ln & 15);
    const int mc = (ln >> 4) * 8;
    const float* src = Vg + (size_t)(b * T_ + t) * M_ + m0 + mc;
    const float4 a = *reinterpret_cast<const float4*>(src);
    const float4 d = *reinterpret_cast<const float4*>(src + 4);
    f16x8 o;
    o[0] = (f16)a.x; o[1] = (f16)a.y; o[2] = (f16)a.z; o[3] = (f16)a.w;
    o[4] = (f16)d.x; o[5] = (f16)d.y; o[6] = (f16)d.z; o[7] = (f16)d.w;
    *reinterpret_cast<f16x8*>(pv + ((size_t)bx * 2048 + task) * 8) = o;
  }
}

// -- main: producer-consumer, MERGED MFMA phases (S(dt) || PV(dt-1)), depth-2 K ring --
__global__ __launch_bounds__(512, 2) void fattn(
    const float* __restrict__ Qg, const f16* __restrict__ pk,
    const f16* __restrict__ pv, float* __restrict__ Og)
{
  __shared__ __align__(16) f16 Ks3[3 * KT_F16];  // 96KB 3-buffer ring
  __shared__ __align__(16) f16 Ps[2][NBLK * 32]; // 2 x 4KB
  __shared__ float redmax[2][NBLK];
  __shared__ float redsum[2][NBLK];
  __shared__ float stat_al[2][NBLK];
  __shared__ float stat_il[NBLK];

  const int raw = blockIdx.x;
  const int bid = (raw & 7) * 64 + (raw >> 3);   // XCD <-> batch (L2 locality)
  const int b   = bid >> 6;
  const int nb  = (bid & 63) << 6;
  const int tid  = threadIdx.x;
  const int wv   = tid >> 6;
  const int lane = tid & 63;
  const int l15  = lane & 15;
  const int lq   = lane >> 4;

  const char* kbase = (const char*)(pk + (size_t)b * NT * KT_F16);
  const f16*  pvb   = pv + (size_t)b * NT * VT_F16;
  const int lo = wv * 4096;                      // per-wave 4KB slice of a 32KB tile

  // prologue: all 8 waves stage K0 -> ring0, K1 -> ring1
  #pragma unroll
  for (int r = 0; r < 4; ++r)
    gld16(kbase + lo + r * 1024 + lane * 16, (char*)&Ks3[0] + lo + r * 1024 + lane * 16);
  #pragma unroll
  for (int r = 0; r < 4; ++r)
    gld16(kbase + (KT_F16 * 2) + lo + r * 1024 + lane * 16,
          (char*)&Ks3[KT_F16] + lo + r * 1024 + lane * 16);

  if (wv < 4) {
    // ================== S-GROUP: wave = (nh = wv>>1, mh = wv&1) ==================
    const int nh = wv >> 1;
    const int mh = wv & 1;
    const int n0 = nh * 32 + l15;
    const int n1 = n0 + 16;

    f16x8 qh0[16], qh1[16];
    {
      const float* qrow0 = Qg + (size_t)(b * N_ + nb + nh * 32 + l15) * T_;
      const float* qrow1 = qrow0 + (size_t)16 * T_;
      #pragma unroll
      for (int ks = 0; ks < 16; ++ks) {
        const int k0 = ks * 32 + lq * 8;
        float f[8];
        *reinterpret_cast<float4*>(&f[0]) = *reinterpret_cast<const float4*>(qrow0 + k0);
        *reinterpret_cast<float4*>(&f[4]) = *reinterpret_cast<const float4*>(qrow0 + k0 + 4);
        f16x8 h;
        #pragma unroll
        for (int j = 0; j < 8; ++j) h[j] = (f16)f[j];
        qh0[ks] = h;
        *reinterpret_cast<float4*>(&f[0]) = *reinterpret_cast<const float4*>(qrow1 + k0);
        *reinterpret_cast<float4*>(&f[4]) = *reinterpret_cast<const float4*>(qrow1 + k0 + 4);
        #pragma unroll
        for (int j = 0; j < 8; ++j) h[j] = (f16)f[j];
        qh1[ks] = h;
      }
    }

    float m_run0 = -INFINITY, m_run1 = -INFINITY;
    float l_par0 = 0.f, l_par1 = 0.f;

    const int mrow = mh * 16 + l15;
    const int mb = mrow * T_;
    const int mx = l15 & 7;

    __syncthreads();   // K0,K1 resident

    int rd = 0;   // dt % 3
    for (int dt = 0; dt < NT; ++dt) {
      // stage K(dt+2) -> ring[(rd+2)%3]
      if (dt + 2 < NT) {
        const char* kt = kbase + (size_t)(dt + 2) * (KT_F16 * 2);
        int st = rd + 2; if (st >= 3) st -= 3;
        char* kd = (char*)&Ks3[0] + (size_t)st * (KT_F16 * 2) + lo;
        #pragma unroll
        for (int r = 0; r < 4; ++r)
          gld16(kt + lo + r * 1024 + lane * 16, kd + r * 1024 + lane * 16);
      }

      // phase1: S^T (PV group runs PV(dt-1) concurrently)
      f32x4 s0 = f32x4{0.f, 0.f, 0.f, 0.f};
      f32x4 s1 = f32x4{0.f, 0.f, 0.f, 0.f};
      {
        const f16* KsC = &Ks3[0] + (size_t)rd * KT_F16;
        __builtin_amdgcn_s_setprio(1);
        #pragma unroll
        for (int ks = 0; ks < 16; ++ks) {
          const int c = ((ks << 2) + lq) ^ mx;
          const f16x8 a = *reinterpret_cast<const f16x8*>(KsC + mb + c * 8);
          s0 = __builtin_amdgcn_mfma_f32_16x16x32_f16(a, qh0[ks], s0, 0, 0, 0);
          s1 = __builtin_amdgcn_mfma_f32_16x16x32_f16(a, qh1[ks], s1, 0, 0, 0);
        }
        __builtin_amdgcn_s_setprio(0);
      }
      float t0 = fmaxf(fmaxf(s0[0], s0[1]), fmaxf(s0[2], s0[3]));
      float t1 = fmaxf(fmaxf(s1[0], s1[1]), fmaxf(s1[2], s1[3]));
      t0 = fmaxf(t0, __shfl_xor(t0, 16)); t0 = fmaxf(t0, __shfl_xor(t0, 32));
      t1 = fmaxf(t1, __shfl_xor(t1, 16)); t1 = fmaxf(t1, __shfl_xor(t1, 32));
      if (lane < 16) {
        redmax[mh][nh * 32 + lane] = t0;
        redmax[mh][nh * 32 + 16 + lane] = t1;
      }
      asm volatile("s_waitcnt lgkmcnt(0)" ::: "memory");
      __builtin_amdgcn_s_barrier();                      // B1
      __builtin_amdgcn_sched_barrier(0);

      // phase2: softmax only
      const int cur = dt & 1;
      const float g0 = fmaxf(redmax[0][n0], redmax[1][n0]);
      const float g1 = fmaxf(redmax[0][n1], redmax[1][n1]);
      const float mnew0 = fmaxf(m_run0, g0);
      const float mnew1 = fmaxf(m_run1, g1);
      const float alpha0 = __expf(m_run0 - mnew0);
      const float alpha1 = __expf(m_run1 - mnew1);
      if (mh == 0 && lane < 16) {
        stat_al[cur][nh * 32 + lane] = alpha0;
        stat_al[cur][nh * 32 + 16 + lane] = alpha1;
      }
      const float e00 = __expf(s0[0] - mnew0);
      const float e01 = __expf(s0[1] - mnew0);
      const float e02 = __expf(s0[2] - mnew0);
      const float e03 = __expf(s0[3] - mnew0);
      const float e10 = __expf(s1[0] - mnew1);
      const float e11 = __expf(s1[1] - mnew1);
      const float e12 = __expf(s1[2] - mnew1);
      const float e13 = __expf(s1[3] - mnew1);
      l_par0 = l_par0 * alpha0 + ((e00 + e01) + (e02 + e03));
      l_par1 = l_par1 * alpha1 + ((e10 + e11) + (e12 + e13));
      m_run0 = mnew0; m_run1 = mnew1;
      {
        f16x4 w0, w1;
        w0[0] = (f16)e00; w0[1] = (f16)e01; w0[2] = (f16)e02; w0[3] = (f16)e03;
        w1[0] = (f16)e10; w1[1] = (f16)e11; w1[2] = (f16)e12; w1[3] = (f16)e13;
        const int ch = mh * 2 + (lq >> 1);
        const int e = (lq & 1) * 4;
        *reinterpret_cast<f16x4*>(&Ps[cur][n0 * 32 + ((ch ^ ((n0 >> 1) & 3)) * 8) + e]) = w0;
        *reinterpret_cast<f16x4*>(&Ps[cur][n1 * 32 + ((ch ^ ((n1 >> 1) & 3)) * 8) + e]) = w1;
      }
      asm volatile("s_waitcnt lgkmcnt(0) vmcnt(4)" ::: "memory");  // K(dt+1) done; K(dt+2) in flight
      __builtin_amdgcn_s_barrier();                      // EB
      __builtin_amdgcn_sched_barrier(0);
      rd = (rd + 1 == 3) ? 0 : rd + 1;
    }

    // epilogue: reduce l over lq, publish 1/l
    l_par0 += __shfl_xor(l_par0, 16); l_par0 += __shfl_xor(l_par0, 32);
    l_par1 += __shfl_xor(l_par1, 16); l_par1 += __shfl_xor(l_par1, 32);
    if (lane < 16) {
      redsum[mh][nh * 32 + lane] = l_par0;
      redsum[mh][nh * 32 + 16 + lane] = l_par1;
    }
    __syncthreads();   // X1
    if (mh == 0 && lane < 16) {
      const int na = nh * 32 + lane;
      const int nbq = na + 16;
      stat_il[na] = 1.0f / (redsum[0][na] + redsum[1][na]);
      stat_il[nbq] = 1.0f / (redsum[0][nbq] + redsum[1][nbq]);
    }
    __syncthreads();   // X2
  } else {
    // ===== PV-GROUP: wave owns t in [(wv-4)*128, +128); PV(dt-1) in phase1 =====
    const int pw = wv - 4;
    const int tb = pw * 128;

    f32x4 oacc[8][4];
    #pragma unroll
    for (int tf = 0; tf < 8; ++tf)
      #pragma unroll
      for (int nf = 0; nf < 4; ++nf)
        oacc[tf][nf] = f32x4{0.f, 0.f, 0.f, 0.f};
    f16x8 vfrA[8], vfrB[8];   // static names (rule-#20)

    __syncthreads();   // K0,K1 resident

    int rdp = 0;   // dt % 3
    for (int dt = 0; dt < NT; dt += 2) {
      // ======== even tile dt: prv buffers = Ps[1]/stat_al[1]/vfrB ========
      {
        if (dt + 2 < NT) {
          const char* kt = kbase + (size_t)(dt + 2) * (KT_F16 * 2);
          int st = rdp + 2; if (st >= 3) st -= 3;
          char* kd = (char*)&Ks3[0] + (size_t)st * (KT_F16 * 2) + lo;
          #pragma unroll
          for (int r = 0; r < 4; ++r)
            gld16(kt + lo + r * 1024 + lane * 16, kd + r * 1024 + lane * 16);
        }
        // issue V(dt) -> vfrA (independent of vfrB below)
        {
          const f16* vt = pvb + (size_t)dt * 2048 * 8;
          #pragma unroll
          for (int tf = 0; tf < 8; ++tf)
            vfrA[tf] = *reinterpret_cast<const f16x8*>(
                vt + ((size_t)(pw * 8 + tf) * 64 + lane) * 8);
        }
        if (dt > 0) {
          const float al0 = stat_al[1][l15];
          const float al1 = stat_al[1][16 + l15];
          const float al2 = stat_al[1][32 + l15];
          const float al3 = stat_al[1][48 + l15];
          if (__any((al0 != 1.0f) || (al1 != 1.0f) || (al2 != 1.0f) || (al3 != 1.0f))) {
            #pragma unroll
            for (int nf = 0; nf < 4; ++nf) {
              const float av = nf == 0 ? al0 : (nf == 1 ? al1 : (nf == 2 ? al2 : al3));
              #pragma unroll
              for (int tf = 0; tf < 8; ++tf) {
                oacc[tf][nf][0] *= av; oacc[tf][nf][1] *= av;
                oacc[tf][nf][2] *= av; oacc[tf][nf][3] *= av;
              }
            }
          }
          // PV(dt-1) concurrent with S(dt)-MFMA
          __builtin_amdgcn_s_setprio(1);
          #pragma unroll
          for (int nf = 0; nf < 4; ++nf) {
            const int n2 = nf * 16 + l15;
            const f16x8 pfr = *reinterpret_cast<const f16x8*>(
                &Ps[1][n2 * 32 + (lq ^ ((n2 >> 1) & 3)) * 8]);
            #pragma unroll
            for (int tf = 0; tf < 8; ++tf)
              oacc[tf][nf] = __builtin_amdgcn_mfma_f32_16x16x32_f16(vfrB[tf], pfr, oacc[tf][nf], 0, 0, 0);
          }
          __builtin_amdgcn_s_setprio(0);
        }
        __builtin_amdgcn_s_barrier();                    // B1
        __builtin_amdgcn_sched_barrier(0);
        // phase2: idle (S softmax)
        asm volatile("s_waitcnt vmcnt(12)" ::: "memory"); // K(dt+1) done (FIFO)
        __builtin_amdgcn_s_barrier();                    // EB
        __builtin_amdgcn_sched_barrier(0);
        rdp = (rdp + 1 == 3) ? 0 : rdp + 1;
      }
      // ======== odd tile dt+1: prv = Ps[0]/stat_al[0]/vfrA ========
      {
        if (dt + 3 < NT) {
          const char* kt = kbase + (size_t)(dt + 3) * (KT_F16 * 2);
          int st = rdp + 2; if (st >= 3) st -= 3;
          char* kd = (char*)&Ks3[0] + (size_t)st * (KT_F16 * 2) + lo;
          #pragma unroll
          for (int r = 0; r < 4; ++r)
            gld16(kt + lo + r * 1024 + lane * 16, kd + r * 1024 + lane * 16);
        }
        {
          const f16* vt = pvb + (size_t)(dt + 1) * 2048 * 8;
          #pragma unroll
          for (int tf = 0; tf < 8; ++tf)
            vfrB[tf] = *reinterpret_cast<const f16x8*>(
                vt + ((size_t)(pw * 8 + tf) * 64 + lane) * 8);
        }
        {
          const float al0 = stat_al[0][l15];
          const float al1 = stat_al[0][16 + l15];
          const float al2 = stat_al[0][32 + l15];
          const float al3 = stat_al[0][48 + l15];
          if (__any((al0 != 1.0f) || (al1 != 1.0f) || (al2 != 1.0f) || (al3 != 1.0f))) {
            #pragma unroll
            for (int nf = 0; nf < 4; ++nf) {
              const float av = nf == 0 ? al0 : (nf == 1 ? al1 : (nf == 2 ? al2 : al3));
              #pragma unroll
              for (int tf = 0; tf < 8; ++tf) {
                oacc[tf][nf][0] *= av; oacc[tf][nf][1] *= av;
                oacc[tf][nf][2] *= av; oacc[tf][nf][3] *= av;
              }
            }
          }
          __builtin_amdgcn_s_setprio(1);
          #pragma unroll
          for (int nf = 0; nf < 4; ++nf) {
            const int n2 = nf * 16 + l15;
            const f16x8 pfr = *reinterpret_cast<const f16x8*>(
                &Ps[0][n2 * 32 + (lq ^ ((n2 >> 1) & 3)) * 8]);
            #pragma unroll
            for (int tf = 0; tf < 8; ++tf)
              oacc[tf][nf] = __builtin_amdgcn_mfma_f32_16x16x32_f16(vfrA[tf], pfr, oacc[tf][nf], 0, 0, 0);
          }
          __builtin_amdgcn_s_setprio(0);
        }
        __builtin_amdgcn_s_barrier();                    // B1
        __builtin_amdgcn_sched_barrier(0);
        asm volatile("s_waitcnt vmcnt(12)" ::: "memory");
        __builtin_amdgcn_s_barrier();                    // EB
        __builtin_amdgcn_sched_barrier(0);
        rdp = (rdp + 1 == 3) ? 0 : rdp + 1;
      }
    }

    // epilogue: final PV(NT-1) -> Ps[1]/stat_al[1]/vfrB
    {
      const float al0 = stat_al[1][l15];
      const float al1 = stat_al[1][16 + l15];
      const float al2 = stat_al[1][32 + l15];
      const float al3 = stat_al[1][48 + l15];
      if (__any((al0 != 1.0f) || (al1 != 1.0f) || (al2 != 1.0f) || (al3 != 1.0f))) {
        #pragma unroll
        for (int nf = 0; nf < 4; ++nf) {
          const float av = nf == 0 ? al0 : (nf == 1 ? al1 : (nf == 2 ? al2 : al3));
          #pragma unroll
          for (int tf = 0; tf < 8; ++tf) {
            oacc[tf][nf][0] *= av; oacc[tf][nf][1] *= av;
            oacc[tf][nf][2] *= av; oacc[tf][nf][3] *= av;
          }
        }
      }
      #pragma unroll
      for (int nf = 0; nf < 4; ++nf) {
        const int n2 = nf * 16 + l15;
        const f16x8 pfr = *reinterpret_cast<const f16x8*>(
            &Ps[1][n2 * 32 + (lq ^ ((n2 >> 1) & 3)) * 8]);
        #pragma unroll
        for (int tf = 0; tf < 8; ++tf)
          oacc[tf][nf] = __builtin_amdgcn_mfma_f32_16x16x32_f16(vfrB[tf], pfr, oacc[tf][nf], 0, 0, 0);
      }
    }
    __syncthreads();   // X1 (match S-group)
    __syncthreads();   // X2 (stat_il committed)
    #pragma unroll
    for (int nf = 0; nf < 4; ++nf) {
      const float il = stat_il[nf * 16 + l15];
      const size_t base = (size_t)(b * N_ + nb + nf * 16 + l15) * T_;
      #pragma unroll
      for (int tf = 0; tf < 8; ++tf) {
        const int t = tb + tf * 16 + lq * 4;
        float4 o;
        o.x = oacc[tf][nf][0] * il;
        o.y = oacc[tf][nf][1] * il;
        o.z = oacc[tf][nf][2] * il;
        o.w = oacc[tf][nf][3] * il;
        *reinterpret_cast<float4*>(Og + base + t) = o;
      }
    }
  }
}

// ---------------- fallback (R2-proven, no ws): 8-wave 64-n block ----------------
#define KSTR 520
#define PSTRF 48
__global__ __launch_bounds__(512, 2) void fattn_fb(
    const float* __restrict__ Qg, const float* __restrict__ Kg,
    const float* __restrict__ Vg, float* __restrict__ Og)
{
  __shared__ __align__(16) f16 Ksf[KVB * KSTR];
  __shared__ __align__(16) f16 Vsf[T_ * KVB];
  __shared__ __align__(16) f16 Psf[64 * PSTRF];
  __shared__ float redmax[2][64];
  __shared__ float redsum[2][64];
  __shared__ float stat_al[64];
  __shared__ float stat_il[64];

  const int bid  = blockIdx.x;
  const int b    = bid >> 6;
  const int nb   = (bid & 63) << 6;
  const int tid  = threadIdx.x;
  const int w    = tid >> 6;
  const int lane = tid & 63;
  const int l15  = lane & 15;
  const int lq   = lane >> 4;
  const int ms   = w & 1;
  const int ng   = w >> 1;

  f16x8 qh[16], ql[16];
  {
    const float* qrow = Qg + (size_t)(b * N_ + nb + ng * 16 + l15) * T_;
    #pragma unroll
    for (int ks = 0; ks < 16; ++ks) {
      const int k0 = ks * 32 + lq * 8;
      float f[8];
      *reinterpret_cast<float4*>(&f[0]) = *reinterpret_cast<const float4*>(qrow + k0);
      *reinterpret_cast<float4*>(&f[4]) = *reinterpret_cast<const float4*>(qrow + k0 + 4);
      f16x8 h, l;
      #pragma unroll
      for (int j = 0; j < 8; ++j) { h[j] = (f16)f[j]; l[j] = (f16)(f[j] - (float)h[j]); }
      qh[ks] = h; ql[ks] = l;
    }
  }
  f32x4 oacc[4][4];
  #pragma unroll
  for (int tf = 0; tf < 4; ++tf)
    #pragma unroll
    for (int nf = 0; nf < 4; ++nf)
      oacc[tf][nf] = f32x4{0.f, 0.f, 0.f, 0.f};
  float m_run = -INFINITY, l_run = 0.f;

  for (int mt = 0; mt < M_ / KVB; ++mt) {
    const int m0 = mt * KVB;
    #pragma unroll
    for (int r = 0; r < 8; ++r) {
      const int task = r * 512 + tid;
      const int m  = task & 31;
      const int t0 = (task >> 5) << 2;
      const float* src = Kg + (size_t)(b * T_ + t0) * M_ + m0 + m;
      f16x4 kk;
      kk[0] = (f16)src[0]; kk[1] = (f16)src[M_];
      kk[2] = (f16)src[2 * M_]; kk[3] = (f16)src[3 * M_];
      *reinterpret_cast<f16x4*>(&Ksf[m * KSTR + t0]) = kk;
    }
    #pragma unroll
    for (int r = 0; r < 4; ++r) {
      const int idx = r * 512 + tid;
      const int t  = idx >> 2;
      const int mc = (idx & 3) << 3;
      const float* src = Vg + (size_t)(b * T_ + t) * M_ + m0 + mc;
      const float4 f0 = *reinterpret_cast<const float4*>(src);
      const float4 f1 = *reinterpret_cast<const float4*>(src + 4);
      f16x8 v8;
      v8[0] = (f16)f0.x; v8[1] = (f16)f0.y; v8[2] = (f16)f0.z; v8[3] = (f16)f0.w;
      v8[4] = (f16)f1.x; v8[5] = (f16)f1.y; v8[6] = (f16)f1.z; v8[7] = (f16)f1.w;
      *reinterpret_cast<f16x8*>(&Vsf[t * KVB + (mc ^ ((t & 3) << 3))]) = v8;
    }
    __syncthreads();
    f32x4 sacc = f32x4{0.f, 0.f, 0.f, 0.f};
    {
      const int abase = (ms * 16 + l15) * KSTR + lq * 8;
      #pragma unroll
      for (int ks = 0; ks < 16; ++ks) {
        const f16x8 a = *reinterpret_cast<const f16x8*>(&Ksf[abase + ks * 32]);
        sacc = __builtin_amdgcn_mfma_f32_16x16x32_f16(a, qh[ks], sacc, 0, 0, 0);
        sacc = __builtin_amdgcn_mfma_f32_16x16x32_f16(a, ql[ks], sacc, 0, 0, 0);
      }
    }
    const int n = ng * 16 + l15;
    float tmax = fmaxf(fmaxf(sacc[0], sacc[1]), fmaxf(sacc[2], sacc[3]));
    tmax = fmaxf(tmax, __shfl_xor(tmax, 16));
    tmax = fmaxf(tmax, __shfl_xor(tmax, 32));
    if (lane < 16) redmax[ms][ng * 16 + lane] = tmax;
    __syncthreads();
    const float gmax = fmaxf(redmax[0][n], redmax[1][n]);
    const float mnew = fmaxf(m_run, gmax);
    const float alpha = __expf(m_run - mnew);
    if (ms == 0 && lane < 16) stat_al[ng * 16 + lane] = alpha;
    const float p0 = __expf(sacc[0] - mnew);
    const float p1 = __expf(sacc[1] - mnew);
    const float p2 = __expf(sacc[2] - mnew);
    const float p3 = __expf(sacc[3] - mnew);
    float psum = (p0 + p1) + (p2 + p3);
    psum += __shfl_xor(psum, 16);
    psum += __shfl_xor(psum, 32);
    if (lane < 16) redsum[ms][ng * 16 + lane] = psum;
    {
      f16x4 pw;
      pw[0] = (f16)p0; pw[1] = (f16)p1; pw[2] = (f16)p2; pw[3] = (f16)p3;
      *reinterpret_cast<f16x4*>(&Psf[n * PSTRF + ms * 16 + lq * 4]) = pw;
    }
    __syncthreads();
    l_run = l_run * alpha + redsum[0][n] + redsum[1][n];
    m_run = mnew;
    #pragma unroll
    for (int nf = 0; nf < 4; ++nf) {
      const float av = stat_al[nf * 16 + l15];
      #pragma unroll
      for (int tf = 0; tf < 4; ++tf) {
        oacc[tf][nf][0] *= av; oacc[tf][nf][1] *= av;
        oacc[tf][nf][2] *= av; oacc[tf][nf][3] *= av;
      }
    }
    {
      f16x8 vfr[4];
      #pragma unroll
      for (int tf = 0; tf < 4; ++tf) {
        const int t = w * 64 + tf * 16 + l15;
        vfr[tf] = *reinterpret_cast<const f16x8*>(&Vsf[t * KVB + ((lq * 8) ^ ((t & 3) << 3))]);
      }
      #pragma unroll
      for (int nf = 0; nf < 4; ++nf) {
        const f16x8 pfr = *reinterpret_cast<const f16x8*>(&Psf[(nf * 16 + l15) * PSTRF + lq * 8]);
        #pragma unroll
        for (int tf = 0; tf < 4; ++tf)
          oacc[tf][nf] = __builtin_amdgcn_mfma_f32_16x16x32_f16(vfr[tf], pfr, oacc[tf][nf], 0, 0, 0);
      }
    }
    __syncthreads();
  }
  if (ms == 0 && lane < 16) stat_il[ng * 16 + lane] = 1.0f / l_run;
  __syncthreads();
  #pragma unroll
  for (int nf = 0; nf < 4; ++nf) {
    const float il = stat_il[nf * 16 + l15];
    const size_t base = (size_t)(b * N_ + nb + nf * 16 + l15) * T_;
    #pragma unroll
    for (int tf = 0; tf < 4; ++tf) {
      const int t = w * 64 + tf * 16 + lq * 4;
      float4 o;
      o.x = oacc[tf][nf][0] * il;
      o.y = oacc[tf][nf][1] * il;
      o.z = oacc[tf][nf][2] * il;
      o.w = oacc[tf][nf][3] * il;
      *reinterpret_cast<float4*>(Og + base + t) = o;
    }
  }
}

extern "C" void kernel_launch(void* const* d_in, const int* in_sizes, int n_in,
                              void* d_out, int out_size, void* d_ws, size_t ws_size,
                              hipStream_t stream) {
  const float* Q = (const float*)d_in[0];
  const float* K = (const float*)d_in[1];
  const float* V = (const float*)d_in[2];
  float* O = (float*)d_out;
  (void)in_sizes; (void)n_in; (void)out_size;

  const size_t needed = (size_t)B_ * NT * KT_F16 * 2 * 2;  // pk + pv = 64MB
  if (ws_size >= needed) {
    f16* pk = (f16*)d_ws;
    f16* pv = pk + (size_t)B_ * NT * KT_F16;
    pack_k<<<dim3(B_ * NT * 8), dim3(256), 0, stream>>>(K, pk);
    pack_v<<<dim3(B_ * NT), dim3(256), 0, stream>>>(V, pv);
    fattn<<<dim3(B_ * (N_ / NBLK)), dim3(512), 0, stream>>>(Q, pk, pv, O);
  } else {
    fattn_fb<<<dim3(B_ * (N_ / NBLK)), dim3(512), 0, stream>>>(Q, K, V, O);
  }
}

// Round 14
// 349.353 us; speedup vs baseline: 2.3264x; 1.2319x over previous
//
#include <hip/hip_runtime.h>
#include <hip/hip_bf16.h>
#include <stdint.h>

#define B_ 8
#define N_ 4096
#define T_ 512
#define M_ 4096
#define KVB 32
#define NBLK 64
#define NT 128            // 32-m tiles
#define KT_F16 (KVB*T_)   // 16384 f16 = 32KB per packed K tile
#define VT_F16 (T_*KVB)   // 16384 f16 = 32KB per packed V tile

typedef _Float16 f16;
typedef __attribute__((ext_vector_type(8))) f16 f16x8;
typedef __attribute__((ext_vector_type(4))) f16 f16x4;
typedef __attribute__((ext_vector_type(4))) float f32x4;

// ---------------- pack kernels ----------------
// K image (NEW, fragment-ordered for direct global->reg S-fragments):
//   per (tile mt, role mh, ks): 64 lanes x 8 f16; lane ln (lq=ln>>4, l15=ln&15)
//   holds fp16 K[b][t = ks*32 + lq*8 .. +8][m0 + mh*16 + l15]
__global__ __launch_bounds__(256) void pack_k(const float* __restrict__ Kg,
                                              f16* __restrict__ pk) {
  const int bx = blockIdx.x;
  const int ts = bx & 7;            // 64-t slab -> ks in {ts*2, ts*2+1}
  const int mt = (bx >> 3) & (NT - 1);
  const int b  = bx >> 10;
  const int m0 = mt * KVB;
  const int tid = threadIdx.x;
  __shared__ float tileT[64][33];
  {
    const int tl = tid >> 2;
    const int mseg = (tid & 3) * 8;
    const float* src = Kg + (size_t)(b * T_ + ts * 64 + tl) * M_ + m0 + mseg;
    const float4 a = *reinterpret_cast<const float4*>(src);
    const float4 c = *reinterpret_cast<const float4*>(src + 4);
    tileT[tl][mseg + 0] = a.x; tileT[tl][mseg + 1] = a.y;
    tileT[tl][mseg + 2] = a.z; tileT[tl][mseg + 3] = a.w;
    tileT[tl][mseg + 4] = c.x; tileT[tl][mseg + 5] = c.y;
    tileT[tl][mseg + 6] = c.z; tileT[tl][mseg + 7] = c.w;
  }
  __syncthreads();
  {
    // one 16B fragment-chunk per thread: 2(mh) x 2(ksl) x 64(ln) = 256
    const int mh  = tid >> 7;
    const int ksl = (tid >> 6) & 1;
    const int ln  = tid & 63;
    const int lq  = ln >> 4;
    const int lm  = ln & 15;
    const int ks  = ts * 2 + ksl;
    f16x8 o;
    #pragma unroll
    for (int j = 0; j < 8; ++j)
      o[j] = (f16)tileT[ksl * 32 + lq * 8 + j][mh * 16 + lm];
    f16* dst = pk + ((((size_t)(b * NT + mt) * 2 + mh) * 16 + ks) * 512) + ln * 8;
    *reinterpret_cast<f16x8*>(dst) = o;
  }
}

// V image (proven R4..R13): exact PV A-fragment order. Per 32-m tile:
//   [tslot 0..31][lane 0..63]: lane holds fp16 V[b][tslot*16+(lane&15)][m0+(lane>>4)*8 ..+8]
__global__ __launch_bounds__(256) void pack_v(const float* __restrict__ Vg,
                                              f16* __restrict__ pv) {
  const int bx = blockIdx.x;        // b*NT + mt
  const int mt = bx & (NT - 1);
  const int b  = bx >> 7;
  const int m0 = mt * KVB;
  const int tid = threadIdx.x;
  #pragma unroll
  for (int it = 0; it < 8; ++it) {
    const int task = it * 256 + tid;      // 0..2047
    const int ts = task >> 6;
    const int ln = task & 63;
    const int t  = ts * 16 + (ln & 15);
    const int mc = (ln >> 4) * 8;
    const float* src = Vg + (size_t)(b * T_ + t) * M_ + m0 + mc;
    const float4 a = *reinterpret_cast<const float4*>(src);
    const float4 d = *reinterpret_cast<const float4*>(src + 4);
    f16x8 o;
    o[0] = (f16)a.x; o[1] = (f16)a.y; o[2] = (f16)a.z; o[3] = (f16)a.w;
    o[4] = (f16)d.x; o[5] = (f16)d.y; o[6] = (f16)d.z; o[7] = (f16)d.w;
    *reinterpret_cast<f16x8*>(pv + ((size_t)bx * 2048 + task) * 8) = o;
  }
}

// --- main: producer-consumer, K streamed global->reg (NO K in LDS), tiny LDS ---
__global__ __launch_bounds__(512, 2) void fattn(
    const float* __restrict__ Qg, const f16* __restrict__ pk,
    const f16* __restrict__ pv, float* __restrict__ Og)
{
  __shared__ __align__(16) f16 Ps[2][NBLK * 32]; // 2 x 4KB: [n][m], chunk-XOR
  __shared__ float redmax[2][NBLK];
  __shared__ float redsum[2][NBLK];
  __shared__ float stat_al[2][NBLK];
  __shared__ float stat_il[NBLK];

  const int raw = blockIdx.x;
  const int bid = (raw & 7) * 64 + (raw >> 3);   // XCD <-> batch (L2 locality)
  const int b   = bid >> 6;
  const int nb  = (bid & 63) << 6;
  const int tid  = threadIdx.x;
  const int wv   = tid >> 6;
  const int lane = tid & 63;
  const int l15  = lane & 15;
  const int lq   = lane >> 4;

  const f16* pkb = pk + (size_t)b * NT * KT_F16;
  const f16* pvb = pv + (size_t)b * NT * VT_F16;

  if (wv < 4) {
    // ================== S-GROUP: wave = (nh = wv>>1, mh = wv&1) ==================
    const int nh = wv >> 1;
    const int mh = wv & 1;
    const int n0 = nh * 32 + l15;
    const int n1 = n0 + 16;
    const f16* kmh = pkb + (size_t)mh * 8192;   // + dt*16384

    // K fragments for tile 0 -> regs (single-buffered, reloaded post-consume)
    f16x8 kfr[16];
    #pragma unroll
    for (int ks = 0; ks < 16; ++ks)
      kfr[ks] = *reinterpret_cast<const f16x8*>(kmh + (size_t)ks * 512 + lane * 8);

    // Q fragments: two 16-n sets, fp16 (validated numerics: absmax 0.047 < 0.1025)
    f16x8 qh0[16], qh1[16];
    {
      const float* qrow0 = Qg + (size_t)(b * N_ + nb + nh * 32 + l15) * T_;
      const float* qrow1 = qrow0 + (size_t)16 * T_;
      #pragma unroll
      for (int ks = 0; ks < 16; ++ks) {
        const int k0 = ks * 32 + lq * 8;
        float f[8];
        *reinterpret_cast<float4*>(&f[0]) = *reinterpret_cast<const float4*>(qrow0 + k0);
        *reinterpret_cast<float4*>(&f[4]) = *reinterpret_cast<const float4*>(qrow0 + k0 + 4);
        f16x8 h;
        #pragma unroll
        for (int j = 0; j < 8; ++j) h[j] = (f16)f[j];
        qh0[ks] = h;
        *reinterpret_cast<float4*>(&f[0]) = *reinterpret_cast<const float4*>(qrow1 + k0);
        *reinterpret_cast<float4*>(&f[4]) = *reinterpret_cast<const float4*>(qrow1 + k0 + 4);
        #pragma unroll
        for (int j = 0; j < 8; ++j) h[j] = (f16)f[j];
        qh1[ks] = h;
      }
    }

    float m_run0 = -INFINITY, m_run1 = -INFINITY;
    float l_par0 = 0.f, l_par1 = 0.f;

    for (int dt = 0; dt < NT; ++dt) {
      // phase1: S^T from registers (PV group runs PV(dt-1) concurrently)
      f32x4 s0 = f32x4{0.f, 0.f, 0.f, 0.f};
      f32x4 s1 = f32x4{0.f, 0.f, 0.f, 0.f};
      __builtin_amdgcn_s_setprio(1);
      #pragma unroll
      for (int ks = 0; ks < 16; ++ks) {
        s0 = __builtin_amdgcn_mfma_f32_16x16x32_f16(kfr[ks], qh0[ks], s0, 0, 0, 0);
        s1 = __builtin_amdgcn_mfma_f32_16x16x32_f16(kfr[ks], qh1[ks], s1, 0, 0, 0);
      }
      __builtin_amdgcn_s_setprio(0);

      // reload kfr <- K(dt+1) (anti-dep: issues after the MFMAs above read kfr;
      // ~full softmax+PV window to cover L2 latency before next use)
      if (dt + 1 < NT) {
        const f16* kp = kmh + (size_t)(dt + 1) * KT_F16;
        #pragma unroll
        for (int ks = 0; ks < 16; ++ks)
          kfr[ks] = *reinterpret_cast<const f16x8*>(kp + (size_t)ks * 512 + lane * 8);
      }

      float t0 = fmaxf(fmaxf(s0[0], s0[1]), fmaxf(s0[2], s0[3]));
      float t1 = fmaxf(fmaxf(s1[0], s1[1]), fmaxf(s1[2], s1[3]));
      t0 = fmaxf(t0, __shfl_xor(t0, 16)); t0 = fmaxf(t0, __shfl_xor(t0, 32));
      t1 = fmaxf(t1, __shfl_xor(t1, 16)); t1 = fmaxf(t1, __shfl_xor(t1, 32));
      if (lane < 16) {
        redmax[mh][nh * 32 + lane] = t0;
        redmax[mh][nh * 32 + 16 + lane] = t1;
      }
      asm volatile("s_waitcnt lgkmcnt(0)" ::: "memory");
      __builtin_amdgcn_s_barrier();                      // B1
      __builtin_amdgcn_sched_barrier(0);

      // phase2: softmax only
      const int cur = dt & 1;
      const float g0 = fmaxf(redmax[0][n0], redmax[1][n0]);
      const float g1 = fmaxf(redmax[0][n1], redmax[1][n1]);
      const float mnew0 = fmaxf(m_run0, g0);
      const float mnew1 = fmaxf(m_run1, g1);
      const float alpha0 = __expf(m_run0 - mnew0);       // first tile: 0
      const float alpha1 = __expf(m_run1 - mnew1);
      if (mh == 0 && lane < 16) {
        stat_al[cur][nh * 32 + lane] = alpha0;
        stat_al[cur][nh * 32 + 16 + lane] = alpha1;
      }
      const float e00 = __expf(s0[0] - mnew0);
      const float e01 = __expf(s0[1] - mnew0);
      const float e02 = __expf(s0[2] - mnew0);
      const float e03 = __expf(s0[3] - mnew0);
      const float e10 = __expf(s1[0] - mnew1);
      const float e11 = __expf(s1[1] - mnew1);
      const float e12 = __expf(s1[2] - mnew1);
      const float e13 = __expf(s1[3] - mnew1);
      l_par0 = l_par0 * alpha0 + ((e00 + e01) + (e02 + e03));
      l_par1 = l_par1 * alpha1 + ((e10 + e11) + (e12 + e13));
      m_run0 = mnew0; m_run1 = mnew1;
      {
        f16x4 w0, w1;
        w0[0] = (f16)e00; w0[1] = (f16)e01; w0[2] = (f16)e02; w0[3] = (f16)e03;
        w1[0] = (f16)e10; w1[1] = (f16)e11; w1[2] = (f16)e12; w1[3] = (f16)e13;
        const int ch = mh * 2 + (lq >> 1);
        const int e = (lq & 1) * 4;
        *reinterpret_cast<f16x4*>(&Ps[cur][n0 * 32 + ((ch ^ ((n0 >> 1) & 3)) * 8) + e]) = w0;
        *reinterpret_cast<f16x4*>(&Ps[cur][n1 * 32 + ((ch ^ ((n1 >> 1) & 3)) * 8) + e]) = w1;
      }
      asm volatile("s_waitcnt lgkmcnt(0)" ::: "memory");
      __builtin_amdgcn_s_barrier();                      // EB
      __builtin_amdgcn_sched_barrier(0);
    }

    // epilogue: reduce l over lq, publish 1/l
    l_par0 += __shfl_xor(l_par0, 16); l_par0 += __shfl_xor(l_par0, 32);
    l_par1 += __shfl_xor(l_par1, 16); l_par1 += __shfl_xor(l_par1, 32);
    if (lane < 16) {
      redsum[mh][nh * 32 + lane] = l_par0;
      redsum[mh][nh * 32 + 16 + lane] = l_par1;
    }
    __syncthreads();   // X1
    if (mh == 0 && lane < 16) {
      const int na = nh * 32 + lane;
      const int nbq = na + 16;
      stat_il[na] = 1.0f / (redsum[0][na] + redsum[1][na]);
      stat_il[nbq] = 1.0f / (redsum[0][nbq] + redsum[1][nbq]);
    }
    __syncthreads();   // X2
  } else {
    // ===== PV-GROUP: wave owns t in [(wv-4)*128, +128); PV(dt-1) in phase1 =====
    const int pw = wv - 4;
    const int tb = pw * 128;

    f32x4 oacc[8][4];
    #pragma unroll
    for (int tf = 0; tf < 8; ++tf)
      #pragma unroll
      for (int nf = 0; nf < 4; ++nf)
        oacc[tf][nf] = f32x4{0.f, 0.f, 0.f, 0.f};
    f16x8 vfrA[8], vfrB[8];   // static names (rule-#20)

    for (int dt = 0; dt < NT; dt += 2) {
      // ======== even tile dt: prv buffers = Ps[1]/stat_al[1]/vfrB ========
      {
        // issue V(dt) -> vfrA
        {
          const f16* vt = pvb + (size_t)dt * 2048 * 8;
          #pragma unroll
          for (int tf = 0; tf < 8; ++tf)
            vfrA[tf] = *reinterpret_cast<const f16x8*>(
                vt + ((size_t)(pw * 8 + tf) * 64 + lane) * 8);
        }
        if (dt > 0) {
          const float al0 = stat_al[1][l15];
          const float al1 = stat_al[1][16 + l15];
          const float al2 = stat_al[1][32 + l15];
          const float al3 = stat_al[1][48 + l15];
          if (__any((al0 != 1.0f) || (al1 != 1.0f) || (al2 != 1.0f) || (al3 != 1.0f))) {
            #pragma unroll
            for (int nf = 0; nf < 4; ++nf) {
              const float av = nf == 0 ? al0 : (nf == 1 ? al1 : (nf == 2 ? al2 : al3));
              #pragma unroll
              for (int tf = 0; tf < 8; ++tf) {
                oacc[tf][nf][0] *= av; oacc[tf][nf][1] *= av;
                oacc[tf][nf][2] *= av; oacc[tf][nf][3] *= av;
              }
            }
          }
          // PV(dt-1) concurrent with S(dt)-MFMA
          __builtin_amdgcn_s_setprio(1);
          #pragma unroll
          for (int nf = 0; nf < 4; ++nf) {
            const int n2 = nf * 16 + l15;
            const f16x8 pfr = *reinterpret_cast<const f16x8*>(
                &Ps[1][n2 * 32 + (lq ^ ((n2 >> 1) & 3)) * 8]);
            #pragma unroll
            for (int tf = 0; tf < 8; ++tf)
              oacc[tf][nf] = __builtin_amdgcn_mfma_f32_16x16x32_f16(vfrB[tf], pfr, oacc[tf][nf], 0, 0, 0);
          }
          __builtin_amdgcn_s_setprio(0);
        }
        __builtin_amdgcn_s_barrier();                    // B1
        __builtin_amdgcn_sched_barrier(0);
        // phase2: idle (S softmax)
        __builtin_amdgcn_s_barrier();                    // EB
        __builtin_amdgcn_sched_barrier(0);
      }
      // ======== odd tile dt+1: prv = Ps[0]/stat_al[0]/vfrA ========
      {
        {
          const f16* vt = pvb + (size_t)(dt + 1) * 2048 * 8;
          #pragma unroll
          for (int tf = 0; tf < 8; ++tf)
            vfrB[tf] = *reinterpret_cast<const f16x8*>(
                vt + ((size_t)(pw * 8 + tf) * 64 + lane) * 8);
        }
        {
          const float al0 = stat_al[0][l15];
          const float al1 = stat_al[0][16 + l15];
          const float al2 = stat_al[0][32 + l15];
          const float al3 = stat_al[0][48 + l15];
          if (__any((al0 != 1.0f) || (al1 != 1.0f) || (al2 != 1.0f) || (al3 != 1.0f))) {
            #pragma unroll
            for (int nf = 0; nf < 4; ++nf) {
              const float av = nf == 0 ? al0 : (nf == 1 ? al1 : (nf == 2 ? al2 : al3));
              #pragma unroll
              for (int tf = 0; tf < 8; ++tf) {
                oacc[tf][nf][0] *= av; oacc[tf][nf][1] *= av;
                oacc[tf][nf][2] *= av; oacc[tf][nf][3] *= av;
              }
            }
          }
          __builtin_amdgcn_s_setprio(1);
          #pragma unroll
          for (int nf = 0; nf < 4; ++nf) {
            const int n2 = nf * 16 + l15;
            const f16x8 pfr = *reinterpret_cast<const f16x8*>(
                &Ps[0][n2 * 32 + (lq ^ ((n2 >> 1) & 3)) * 8]);
            #pragma unroll
            for (int tf = 0; tf < 8; ++tf)
              oacc[tf][nf] = __builtin_amdgcn_mfma_f32_16x16x32_f16(vfrA[tf], pfr, oacc[tf][nf], 0, 0, 0);
          }
          __builtin_amdgcn_s_setprio(0);
        }
        __builtin_amdgcn_s_barrier();                    // B1
        __builtin_amdgcn_sched_barrier(0);
        __builtin_amdgcn_s_barrier();                    // EB
        __builtin_amdgcn_sched_barrier(0);
      }
    }

    // epilogue: final PV(NT-1) -> Ps[1]/stat_al[1]/vfrB
    {
      const float al0 = stat_al[1][l15];
      const float al1 = stat_al[1][16 + l15];
      const float al2 = stat_al[1][32 + l15];
      const float al3 = stat_al[1][48 + l15];
      if (__any((al0 != 1.0f) || (al1 != 1.0f) || (al2 != 1.0f) || (al3 != 1.0f))) {
        #pragma unroll
        for (int nf = 0; nf < 4; ++nf) {
          const float av = nf == 0 ? al0 : (nf == 1 ? al1 : (nf == 2 ? al2 : al3));
          #pragma unroll
          for (int tf = 0; tf < 8; ++tf) {
            oacc[tf][nf][0] *= av; oacc[tf][nf][1] *= av;
            oacc[tf][nf][2] *= av; oacc[tf][nf][3] *= av;
          }
        }
      }
      #pragma unroll
      for (int nf = 0; nf < 4; ++nf) {
        const int n2 = nf * 16 + l15;
        const f16x8 pfr = *reinterpret_cast<const f16x8*>(
            &Ps[1][n2 * 32 + (lq ^ ((n2 >> 1) & 3)) * 8]);
        #pragma unroll
        for (int tf = 0; tf < 8; ++tf)
          oacc[tf][nf] = __builtin_amdgcn_mfma_f32_16x16x32_f16(vfrB[tf], pfr, oacc[tf][nf], 0, 0, 0);
      }
    }
    __syncthreads();   // X1 (match S-group)
    __syncthreads();   // X2 (stat_il committed)
    #pragma unroll
    for (int nf = 0; nf < 4; ++nf) {
      const float il = stat_il[nf * 16 + l15];
      const size_t base = (size_t)(b * N_ + nb + nf * 16 + l15) * T_;
      #pragma unroll
      for (int tf = 0; tf < 8; ++tf) {
        const int t = tb + tf * 16 + lq * 4;
        float4 o;
        o.x = oacc[tf][nf][0] * il;
        o.y = oacc[tf][nf][1] * il;
        o.z = oacc[tf][nf][2] * il;
        o.w = oacc[tf][nf][3] * il;
        *reinterpret_cast<float4*>(Og + base + t) = o;
      }
    }
  }
}

// ---------------- fallback (R2-proven, no ws): 8-wave 64-n block ----------------
#define KSTR 520
#define PSTRF 48
__global__ __launch_bounds__(512, 2) void fattn_fb(
    const float* __restrict__ Qg, const float* __restrict__ Kg,
    const float* __restrict__ Vg, float* __restrict__ Og)
{
  __shared__ __align__(16) f16 Ksf[KVB * KSTR];
  __shared__ __align__(16) f16 Vsf[T_ * KVB];
  __shared__ __align__(16) f16 Psf[64 * PSTRF];
  __shared__ float redmax[2][64];
  __shared__ float redsum[2][64];
  __shared__ float stat_al[64];
  __shared__ float stat_il[64];

  const int bid  = blockIdx.x;
  const int b    = bid >> 6;
  const int nb   = (bid & 63) << 6;
  const int tid  = threadIdx.x;
  const int w    = tid >> 6;
  const int lane = tid & 63;
  const int l15  = lane & 15;
  const int lq   = lane >> 4;
  const int ms   = w & 1;
  const int ng   = w >> 1;

  f16x8 qh[16], ql[16];
  {
    const float* qrow = Qg + (size_t)(b * N_ + nb + ng * 16 + l15) * T_;
    #pragma unroll
    for (int ks = 0; ks < 16; ++ks) {
      const int k0 = ks * 32 + lq * 8;
      float f[8];
      *reinterpret_cast<float4*>(&f[0]) = *reinterpret_cast<const float4*>(qrow + k0);
      *reinterpret_cast<float4*>(&f[4]) = *reinterpret_cast<const float4*>(qrow + k0 + 4);
      f16x8 h, l;
      #pragma unroll
      for (int j = 0; j < 8; ++j) { h[j] = (f16)f[j]; l[j] = (f16)(f[j] - (float)h[j]); }
      qh[ks] = h; ql[ks] = l;
    }
  }
  f32x4 oacc[4][4];
  #pragma unroll
  for (int tf = 0; tf < 4; ++tf)
    #pragma unroll
    for (int nf = 0; nf < 4; ++nf)
      oacc[tf][nf] = f32x4{0.f, 0.f, 0.f, 0.f};
  float m_run = -INFINITY, l_run = 0.f;

  for (int mt = 0; mt < M_ / KVB; ++mt) {
    const int m0 = mt * KVB;
    #pragma unroll
    for (int r = 0; r < 8; ++r) {
      const int task = r * 512 + tid;
      const int m  = task & 31;
      const int t0 = (task >> 5) << 2;
      const float* src = Kg + (size_t)(b * T_ + t0) * M_ + m0 + m;
      f16x4 kk;
      kk[0] = (f16)src[0]; kk[1] = (f16)src[M_];
      kk[2] = (f16)src[2 * M_]; kk[3] = (f16)src[3 * M_];
      *reinterpret_cast<f16x4*>(&Ksf[m * KSTR + t0]) = kk;
    }
    #pragma unroll
    for (int r = 0; r < 4; ++r) {
      const int idx = r * 512 + tid;
      const int t  = idx >> 2;
      const int mc = (idx & 3) << 3;
      const float* src = Vg + (size_t)(b * T_ + t) * M_ + m0 + mc;
      const float4 f0 = *reinterpret_cast<const float4*>(src);
      const float4 f1 = *reinterpret_cast<const float4*>(src + 4);
      f16x8 v8;
      v8[0] = (f16)f0.x; v8[1] = (f16)f0.y; v8[2] = (f16)f0.z; v8[3] = (f16)f0.w;
      v8[4] = (f16)f1.x; v8[5] = (f16)f1.y; v8[6] = (f16)f1.z; v8[7] = (f16)f1.w;
      *reinterpret_cast<f16x8*>(&Vsf[t * KVB + (mc ^ ((t & 3) << 3))]) = v8;
    }
    __syncthreads();
    f32x4 sacc = f32x4{0.f, 0.f, 0.f, 0.f};
    {
      const int abase = (ms * 16 + l15) * KSTR + lq * 8;
      #pragma unroll
      for (int ks = 0; ks < 16; ++ks) {
        const f16x8 a = *reinterpret_cast<const f16x8*>(&Ksf[abase + ks * 32]);
        sacc = __builtin_amdgcn_mfma_f32_16x16x32_f16(a, qh[ks], sacc, 0, 0, 0);
        sacc = __builtin_amdgcn_mfma_f32_16x16x32_f16(a, ql[ks], sacc, 0, 0, 0);
      }
    }
    const int n = ng * 16 + l15;
    float tmax = fmaxf(fmaxf(sacc[0], sacc[1]), fmaxf(sacc[2], sacc[3]));
    tmax = fmaxf(tmax, __shfl_xor(tmax, 16));
    tmax = fmaxf(tmax, __shfl_xor(tmax, 32));
    if (lane < 16) redmax[ms][ng * 16 + lane] = tmax;
    __syncthreads();
    const float gmax = fmaxf(redmax[0][n], redmax[1][n]);
    const float mnew = fmaxf(m_run, gmax);
    const float alpha = __expf(m_run - mnew);
    if (ms == 0 && lane < 16) stat_al[ng * 16 + lane] = alpha;
    const float p0 = __expf(sacc[0] - mnew);
    const float p1 = __expf(sacc[1] - mnew);
    const float p2 = __expf(sacc[2] - mnew);
    const float p3 = __expf(sacc[3] - mnew);
    float psum = (p0 + p1) + (p2 + p3);
    psum += __shfl_xor(psum, 16);
    psum += __shfl_xor(psum, 32);
    if (lane < 16) redsum[ms][ng * 16 + lane] = psum;
    {
      f16x4 pw;
      pw[0] = (f16)p0; pw[1] = (f16)p1; pw[2] = (f16)p2; pw[3] = (f16)p3;
      *reinterpret_cast<f16x4*>(&Psf[n * PSTRF + ms * 16 + lq * 4]) = pw;
    }
    __syncthreads();
    l_run = l_run * alpha + redsum[0][n] + redsum[1][n];
    m_run = mnew;
    #pragma unroll
    for (int nf = 0; nf < 4; ++nf) {
      const float av = stat_al[nf * 16 + l15];
      #pragma unroll
      for (int tf = 0; tf < 4; ++tf) {
        oacc[tf][nf][0] *= av; oacc[tf][nf][1] *= av;
        oacc[tf][nf][2] *= av; oacc[tf][nf][3] *= av;
      }
    }
    {
      f16x8 vfr[4];
      #pragma unroll
      for (int tf = 0; tf < 4; ++tf) {
        const int t = w * 64 + tf * 16 + l15;
        vfr[tf] = *reinterpret_cast<const f16x8*>(&Vsf[t * KVB + ((lq * 8) ^ ((t & 3) << 3))]);
      }
      #pragma unroll
      for (int nf = 0; nf < 4; ++nf) {
        const f16x8 pfr = *reinterpret_cast<const f16x8*>(&Psf[(nf * 16 + l15) * PSTRF + lq * 8]);
        #pragma unroll
        for (int tf = 0; tf < 4; ++tf)
          oacc[tf][nf] = __builtin_amdgcn_mfma_f32_16x16x32_f16(vfr[tf], pfr, oacc[tf][nf], 0, 0, 0);
      }
    }
    __syncthreads();
  }
  if (ms == 0 && lane < 16) stat_il[ng * 16 + lane] = 1.0f / l_run;
  __syncthreads();
  #pragma unroll
  for (int nf = 0; nf < 4; ++nf) {
    const float il = stat_il[nf * 16 + l15];
    const size_t base = (size_t)(b * N_ + nb + nf * 16 + l15) * T_;
    #pragma unroll
    for (int tf = 0; tf < 4; ++tf) {
      const int t = w * 64 + tf * 16 + lq * 4;
      float4 o;
      o.x = oacc[tf][nf][0] * il;
      o.y = oacc[tf][nf][1] * il;
      o.z = oacc[tf][nf][2] * il;
      o.w = oacc[tf][nf][3] * il;
      *reinterpret_cast<float4*>(Og + base + t) = o;
    }
  }
}

extern "C" void kernel_launch(void* const* d_in, const int* in_sizes, int n_in,
                              void* d_out, int out_size, void* d_ws, size_t ws_size,
                              hipStream_t stream) {
  const float* Q = (const float*)d_in[0];
  const float* K = (const float*)d_in[1];
  const float* V = (const float*)d_in[2];
  float* O = (float*)d_out;
  (void)in_sizes; (void)n_in; (void)out_size;

  const size_t needed = (size_t)B_ * NT * KT_F16 * 2 * 2;  // pk + pv = 64MB
  if (ws_size >= needed) {
    f16* pk = (f16*)d_ws;
    f16* pv = pk + (size_t)B_ * NT * KT_F16;
    pack_k<<<dim3(B_ * NT * 8), dim3(256), 0, stream>>>(K, pk);
    pack_v<<<dim3(B_ * NT), dim3(256), 0, stream>>>(V, pv);
    fattn<<<dim3(B_ * (N_ / NBLK)), dim3(512), 0, stream>>>(Q, pk, pv, O);
  } else {
    fattn_fb<<<dim3(B_ * (N_ / NBLK)), dim3(512), 0, stream>>>(Q, K, V, O);
  }
}